// Round 7
// baseline (1770.381 us; speedup 1.0000x reference)
//
#include <hip/hip_runtime.h>
#include <math.h>

// ---------------------------------------------------------------------------
// PGCN twin-branch GCN. fp32. R7: R4 GEMM structure (64x128 tile, 8x4/thread,
// kc=64, single-buffer) + transposed-A LDS (AsT[64][65]) so A reads are 2x
// broadcast ds_read_b128 instead of 8x ds_read_b32. B path identical to R4.
// Accumulation order unchanged vs R4 (bitwise-stable). Rest identical to R4.
// ---------------------------------------------------------------------------

#define TPB 256

__device__ __forceinline__ int swz_block(int bid, int nb) {
  int per = nb >> 3;
  return (bid & 7) * per + (bid >> 3);
}

__device__ __forceinline__ void f4fma(float4& a, const float4 b, float s) {
  a.x += b.x * s; a.y += b.y * s; a.z += b.z * s; a.w += b.w * s;
}
__device__ __forceinline__ float4 f4s(const float4 a, float s) {
  return make_float4(a.x * s, a.y * s, a.z * s, a.w * s);
}

// ---------------- CSR build ----------------
__global__ __launch_bounds__(TPB) void count_k(const int* __restrict__ col,
                                               int* __restrict__ cnt, int E) {
  int e = blockIdx.x * TPB + threadIdx.x;
  if (e < E) atomicAdd(&cnt[col[e]], 1);
}

__global__ __launch_bounds__(TPB) void scan1_k(const int* __restrict__ cnt,
                                               int* __restrict__ rowptr,
                                               int* __restrict__ bsum, int N) {
  __shared__ int s[TPB];
  int tid = threadIdx.x;
  int gid = blockIdx.x * TPB + tid;
  int v = (gid < N) ? cnt[gid] : 0;
  s[tid] = v;
  __syncthreads();
  for (int o = 1; o < TPB; o <<= 1) {
    int t = (tid >= o) ? s[tid - o] : 0;
    __syncthreads();
    s[tid] += t;
    __syncthreads();
  }
  if (gid < N) rowptr[gid] = s[tid] - v;
  if (tid == TPB - 1) bsum[blockIdx.x] = s[TPB - 1];
}

__global__ __launch_bounds__(TPB) void scan2_k(int* __restrict__ bsum, int nb) {
  __shared__ int s[TPB];
  int tid = threadIdx.x;
  int v = (tid < nb) ? bsum[tid] : 0;
  s[tid] = v;
  __syncthreads();
  for (int o = 1; o < TPB; o <<= 1) {
    int t = (tid >= o) ? s[tid - o] : 0;
    __syncthreads();
    s[tid] += t;
    __syncthreads();
  }
  if (tid < nb) bsum[tid] = s[tid] - v;
}

__global__ __launch_bounds__(TPB) void scan3_k(int* __restrict__ rowptr,
                                               const int* __restrict__ bsum,
                                               int N, int E) {
  int gid = blockIdx.x * TPB + threadIdx.x;
  if (gid < N) rowptr[gid] += bsum[blockIdx.x];
  if (gid == 0) rowptr[N] = E;
}

__global__ __launch_bounds__(TPB) void fill_k(const int* __restrict__ col,
                                              const int* __restrict__ rowptr,
                                              int* __restrict__ fil,
                                              int* __restrict__ csr, int E) {
  int e = blockIdx.x * TPB + threadIdx.x;
  if (e < E) {
    int c = col[e];
    int p = rowptr[c] + atomicAdd(&fil[c], 1);
    csr[p] = e;
  }
}

__global__ __launch_bounds__(TPB) void sortadj_k(const int* __restrict__ rowptr,
                                                 int* __restrict__ csr, int N) {
  int i = blockIdx.x * TPB + threadIdx.x;
  if (i >= N) return;
  int s = rowptr[i], e = rowptr[i + 1];
  for (int a = s + 1; a < e; ++a) {
    int v = csr[a];
    int b = a - 1;
    while (b >= s && csr[b] > v) { csr[b + 1] = csr[b]; --b; }
    csr[b + 1] = v;
  }
}

__global__ __launch_bounds__(TPB) void deg_k(const int* __restrict__ rowptr,
                                             const int* __restrict__ csr,
                                             const float* __restrict__ ea,
                                             float* __restrict__ dinv, int N) {
  int i = blockIdx.x * TPB + threadIdx.x;
  if (i >= N) return;
  int s = rowptr[i], e = rowptr[i + 1];
  float d0 = 1.f, d1 = 1.f, d2 = 1.f, d3 = 1.f;
  for (int j = s; j < e; ++j) {
    int eid = csr[j];
    float4 w = *reinterpret_cast<const float4*>(&ea[(size_t)eid * 4]);
    d0 += w.x; d1 += w.y; d2 += w.z; d3 += w.w;
  }
  float dO = (float)(e - s) + 1.f;
  dinv[0 * N + i] = 1.f / sqrtf(d0);
  dinv[1 * N + i] = 1.f / sqrtf(d1);
  dinv[2 * N + i] = 1.f / sqrtf(d2);
  dinv[3 * N + i] = 1.f / sqrtf(d3);
  dinv[4 * N + i] = 1.f / sqrtf(dO);
}

__global__ __launch_bounds__(TPB) void eresolve_k(
    const int* __restrict__ csr, const int* __restrict__ erow,
    const float* __restrict__ ea, const float* __restrict__ dinv, int N, int E,
    int* __restrict__ csrSrc, float4* __restrict__ csrW,
    float* __restrict__ csrWO) {
  int j = blockIdx.x * TPB + threadIdx.x;
  if (j >= E) return;
  int eid = csr[j];
  int r = erow[eid];
  float4 a = *reinterpret_cast<const float4*>(&ea[(size_t)eid * 4]);
  csrSrc[j] = r;
  csrW[j] = make_float4(a.x * dinv[r], a.y * dinv[N + r], a.z * dinv[2 * N + r],
                        a.w * dinv[3 * N + r]);
  csrWO[j] = dinv[4 * N + r];
}

// ------------- fused 4-channel gather on raw x -> S0..S3 ----------
__global__ __launch_bounds__(256) void gather4_k(
    const float4* __restrict__ X, const int* __restrict__ rowptr,
    const int* __restrict__ csrSrc, const float4* __restrict__ csrW,
    const float* __restrict__ dinv, int N, float4* __restrict__ S0,
    float4* __restrict__ S1, float4* __restrict__ S2, float4* __restrict__ S3) {
  int sb = swz_block(blockIdx.x, gridDim.x);
  int node = sb * 8 + (threadIdx.x >> 5);
  int l = threadIdx.x & 31;
  int s = rowptr[node], e = rowptr[node + 1];
  float d0 = dinv[node], d1 = dinv[N + node], d2 = dinv[2 * N + node],
        d3 = dinv[3 * N + node];
  float4 xs = X[(size_t)node * 32 + l];
  float4 a0 = f4s(xs, d0), a1 = f4s(xs, d1), a2 = f4s(xs, d2), a3 = f4s(xs, d3);
  int j = s;
  for (; j + 3 < e; j += 4) {
    int r0 = csrSrc[j], r1 = csrSrc[j + 1], r2 = csrSrc[j + 2], r3 = csrSrc[j + 3];
    float4 w0 = csrW[j], w1 = csrW[j + 1], w2 = csrW[j + 2], w3 = csrW[j + 3];
    float4 x0 = X[(size_t)r0 * 32 + l];
    float4 x1 = X[(size_t)r1 * 32 + l];
    float4 x2 = X[(size_t)r2 * 32 + l];
    float4 x3 = X[(size_t)r3 * 32 + l];
    f4fma(a0, x0, w0.x); f4fma(a1, x0, w0.y); f4fma(a2, x0, w0.z); f4fma(a3, x0, w0.w);
    f4fma(a0, x1, w1.x); f4fma(a1, x1, w1.y); f4fma(a2, x1, w1.z); f4fma(a3, x1, w1.w);
    f4fma(a0, x2, w2.x); f4fma(a1, x2, w2.y); f4fma(a2, x2, w2.z); f4fma(a3, x2, w2.w);
    f4fma(a0, x3, w3.x); f4fma(a1, x3, w3.y); f4fma(a2, x3, w3.z); f4fma(a3, x3, w3.w);
  }
  for (; j < e; ++j) {
    int r = csrSrc[j];
    float4 w = csrW[j];
    float4 xr = X[(size_t)r * 32 + l];
    f4fma(a0, xr, w.x); f4fma(a1, xr, w.y); f4fma(a2, xr, w.z); f4fma(a3, xr, w.w);
  }
  size_t o = (size_t)node * 32 + l;
  S0[o] = f4s(a0, d0);
  S1[o] = f4s(a1, d1);
  S2[o] = f4s(a2, d2);
  S3[o] = f4s(a3, d3);
}

// ------------- single-channel gather (ones weights) ----------
__global__ __launch_bounds__(256) void gather1_k(
    const float4* __restrict__ X, const int* __restrict__ rowptr,
    const int* __restrict__ csrSrc, const float* __restrict__ csrWO,
    const float* __restrict__ dinvO, int N, float4* __restrict__ Out) {
  int sb = swz_block(blockIdx.x, gridDim.x);
  int node = sb * 8 + (threadIdx.x >> 5);
  int l = threadIdx.x & 31;
  int s = rowptr[node], e = rowptr[node + 1];
  float di = dinvO[node];
  float4 acc = f4s(X[(size_t)node * 32 + l], di);
  int j = s;
  for (; j + 3 < e; j += 4) {
    int r0 = csrSrc[j], r1 = csrSrc[j + 1], r2 = csrSrc[j + 2], r3 = csrSrc[j + 3];
    float w0 = csrWO[j], w1 = csrWO[j + 1], w2 = csrWO[j + 2], w3 = csrWO[j + 3];
    float4 x0 = X[(size_t)r0 * 32 + l];
    float4 x1 = X[(size_t)r1 * 32 + l];
    float4 x2 = X[(size_t)r2 * 32 + l];
    float4 x3 = X[(size_t)r3 * 32 + l];
    f4fma(acc, x0, w0); f4fma(acc, x1, w1); f4fma(acc, x2, w2); f4fma(acc, x3, w3);
  }
  for (; j < e; ++j) {
    f4fma(acc, X[(size_t)csrSrc[j] * 32 + l], csrWO[j]);
  }
  Out[(size_t)node * 32 + l] = f4s(acc, di);
}

// ---------------- GEMM core (64x128 tile, 8 rows x 4 cols per thread) --------
// AsT[64][65] transposed staging: write bank = (4*c4 + q + r) % 32 -> 2-way.
// A reads: 2x b128 broadcast (2 addrs/wave). B: linear b128 chunks (R4-proven).

__device__ __forceinline__ void stageA_T(const float* __restrict__ A,
                                         float (*__restrict__ AsT)[65],
                                         int rowBase, int kc, int tid) {
#pragma unroll
  for (int i = 0; i < 4; ++i) {
    int u = tid + i * 256;
    int r = u >> 4, c4 = u & 15;
    float4 v = *reinterpret_cast<const float4*>(
        &A[(size_t)(rowBase + r) * 128 + kc + c4 * 4]);
    AsT[c4 * 4 + 0][r] = v.x;
    AsT[c4 * 4 + 1][r] = v.y;
    AsT[c4 * 4 + 2][r] = v.z;
    AsT[c4 * 4 + 3][r] = v.w;
  }
}

__device__ __forceinline__ void stageW(const float* __restrict__ W,
                                       float (*__restrict__ Ws)[128], int kc,
                                       int tid) {
#pragma unroll
  for (int i = 0; i < 8; ++i) {
    int u = tid + i * 256;
    int r = u >> 5, c4 = u & 31;
    *reinterpret_cast<float4*>(&Ws[r][c4 * 4]) =
        *reinterpret_cast<const float4*>(&W[(size_t)(kc + r) * 128 + c4 * 4]);
  }
}

__device__ __forceinline__ void compute64(const float (*__restrict__ AsT)[65],
                                          const float (*__restrict__ Ws)[128],
                                          int tx, int ty, float acc[8][4]) {
#pragma unroll 4
  for (int k = 0; k < 64; ++k) {
    float a[8], b[4];
    *reinterpret_cast<float4*>(&a[0]) =
        *reinterpret_cast<const float4*>(&AsT[k][ty * 8]);
    *reinterpret_cast<float4*>(&a[4]) =
        *reinterpret_cast<const float4*>(&AsT[k][ty * 8 + 4]);
    *reinterpret_cast<float4*>(&b[0]) =
        *reinterpret_cast<const float4*>(&Ws[k][tx * 4]);
#pragma unroll
    for (int j = 0; j < 8; ++j) {
#pragma unroll
      for (int c = 0; c < 4; ++c) acc[j][c] += a[j] * b[c];
    }
  }
}

// C = act(A @ W + bias)
template <bool RELU>
__global__ __launch_bounds__(256) void gemm_epi(const float* __restrict__ A,
                                                const float* __restrict__ Wp,
                                                const float* __restrict__ bias,
                                                float* __restrict__ C, int M) {
  __shared__ float AsT[64][65];
  __shared__ float Ws[64][128];
  int tid = threadIdx.x;
  int tx = tid & 31;   // cols tx*4 .. +3
  int ty = tid >> 5;   // rows ty*8 .. +7
  int rowBase = blockIdx.x * 64;
  float acc[8][4] = {};
  for (int kc = 0; kc < 128; kc += 64) {
    stageA_T(A, AsT, rowBase, kc, tid);
    stageW(Wp, Ws, kc, tid);
    __syncthreads();
    compute64(AsT, Ws, tx, ty, acc);
    __syncthreads();
  }
  float4 bq = *reinterpret_cast<const float4*>(&bias[tx * 4]);
#pragma unroll
  for (int j = 0; j < 8; ++j) {
    float v0 = acc[j][0] + bq.x, v1 = acc[j][1] + bq.y, v2 = acc[j][2] + bq.z,
          v3 = acc[j][3] + bq.w;
    if (RELU) {
      v0 = fmaxf(v0, 0.f); v1 = fmaxf(v1, 0.f); v2 = fmaxf(v2, 0.f); v3 = fmaxf(v3, 0.f);
    }
    size_t r = (size_t)(rowBase + ty * 8 + j) * 128 + tx * 4;
    *reinterpret_cast<float4*>(&C[r]) = make_float4(v0, v1, v2, v3);
  }
}

// g1 = 0.25 * sum_q relu(S_q @ W_q + b_q)
__global__ __launch_bounds__(256) void gemm4_k(
    const float* __restrict__ S0, const float* __restrict__ S1,
    const float* __restrict__ S2, const float* __restrict__ S3,
    const float* __restrict__ W0, const float* __restrict__ W1,
    const float* __restrict__ W2, const float* __restrict__ W3,
    const float* __restrict__ B0, const float* __restrict__ B1,
    const float* __restrict__ B2, const float* __restrict__ B3,
    float* __restrict__ g1, int M) {
  __shared__ float AsT[64][65];
  __shared__ float Ws[64][128];
  const float* Sarr[4] = {S0, S1, S2, S3};
  const float* Warr[4] = {W0, W1, W2, W3};
  const float* Barr[4] = {B0, B1, B2, B3};
  int tid = threadIdx.x;
  int tx = tid & 31;
  int ty = tid >> 5;
  int rowBase = blockIdx.x * 64;
  float facc[8][4] = {};
#pragma unroll 1
  for (int q = 0; q < 4; ++q) {
    const float* A = Sarr[q];
    const float* Wp = Warr[q];
    float acc[8][4] = {};
    for (int kc = 0; kc < 128; kc += 64) {
      stageA_T(A, AsT, rowBase, kc, tid);
      stageW(Wp, Ws, kc, tid);
      __syncthreads();
      compute64(AsT, Ws, tx, ty, acc);
      __syncthreads();
    }
    float4 bq = *reinterpret_cast<const float4*>(&Barr[q][tx * 4]);
#pragma unroll
    for (int j = 0; j < 8; ++j) {
      facc[j][0] += fmaxf(acc[j][0] + bq.x, 0.f) * 0.25f;
      facc[j][1] += fmaxf(acc[j][1] + bq.y, 0.f) * 0.25f;
      facc[j][2] += fmaxf(acc[j][2] + bq.z, 0.f) * 0.25f;
      facc[j][3] += fmaxf(acc[j][3] + bq.w, 0.f) * 0.25f;
    }
  }
#pragma unroll
  for (int j = 0; j < 8; ++j) {
    size_t r = (size_t)(rowBase + ty * 8 + j) * 128 + tx * 4;
    *reinterpret_cast<float4*>(&g1[r]) =
        make_float4(facc[j][0], facc[j][1], facc[j][2], facc[j][3]);
  }
}

// ------------- score -------------
__global__ __launch_bounds__(256) void score_a(
    const float* __restrict__ g1, const float* __restrict__ g2,
    const float* __restrict__ g3, const float* __restrict__ Wrel,
    const float* __restrict__ Wroot, float* __restrict__ trel,
    float* __restrict__ troot, int N) {
  int wave = threadIdx.x >> 6;
  int lane = threadIdx.x & 63;
  int node = blockIdx.x * 4 + wave;
  if (node >= N) return;
  float sr = 0.f, so = 0.f;
#pragma unroll
  for (int t = 0; t < 2; ++t) {
    int f = lane + t * 64;
    float v1 = g1[(size_t)node * 128 + f];
    float v2 = g2[(size_t)node * 128 + f];
    float v3 = g3[(size_t)node * 128 + f];
    sr += v1 * Wrel[f] + v2 * Wrel[128 + f] + v3 * Wrel[256 + f];
    so += v1 * Wroot[f] + v2 * Wroot[128 + f] + v3 * Wroot[256 + f];
  }
  for (int off = 32; off; off >>= 1) {
    sr += __shfl_down(sr, off);
    so += __shfl_down(so, off);
  }
  if (lane == 0) { trel[node] = sr; troot[node] = so; }
}

__global__ __launch_bounds__(TPB) void score_b(
    const int* __restrict__ rowptr, const int* __restrict__ csrSrc,
    const float* __restrict__ trel, const float* __restrict__ troot,
    const float* __restrict__ bs, float* __restrict__ score, int N) {
  int i = blockIdx.x * TPB + threadIdx.x;
  if (i >= N) return;
  float sc = bs[0] + troot[i];
  int s = rowptr[i], e = rowptr[i + 1];
  for (int j = s; j < e; ++j) sc += trel[csrSrc[j]];
  score[i] = sc;
}

// ------------- per-graph top-k (bitonic) + tanh-weighted mean pool -------------
__global__ __launch_bounds__(512) void topk_pool(
    const float* __restrict__ score, const float* __restrict__ g1,
    const float* __restrict__ g2, const float* __restrict__ g3,
    float* __restrict__ r, int half, int npg, int k) {
  __shared__ float key[1024];
  __shared__ int idx[1024];
  __shared__ float wts[512];
  int b = blockIdx.x;
  int tid = threadIdx.x;
  int base = b * npg;
  for (int i = tid; i < 1024; i += 512) {
    key[i] = (i < npg) ? score[base + i] : -3.0e38f;
    idx[i] = i;
  }
  __syncthreads();
  for (int kk = 2; kk <= 1024; kk <<= 1) {
    for (int j = kk >> 1; j > 0; j >>= 1) {
      for (int i = tid; i < 1024; i += 512) {
        int ixj = i ^ j;
        if (ixj > i) {
          bool desc = ((i & kk) == 0);
          float ki = key[i], kj = key[ixj];
          bool sw = desc ? (ki < kj) : (ki > kj);
          if (sw) {
            key[i] = kj; key[ixj] = ki;
            int t = idx[i]; idx[i] = idx[ixj]; idx[ixj] = t;
          }
        }
      }
      __syncthreads();
    }
  }
  if (tid < k) wts[tid] = tanhf(key[tid]);
  __syncthreads();
  if (tid < 384) {
    const float* gp = (tid < 128) ? g1 : ((tid < 256) ? g2 : g3);
    int fo = tid & 127;
    float acc = 0.f;
    for (int j = 0; j < k; ++j) {
      int n = base + idx[j];
      acc += wts[j] * gp[(size_t)n * 128 + fo];
    }
    r[(size_t)b * 768 + half * 384 + tid] = acc / (float)k;
  }
}

// ------------- MLP 768 -> 32 -> 8 -> 2 -------------
__global__ __launch_bounds__(64) void mlp_k(
    const float* __restrict__ r, const float* __restrict__ Wm1,
    const float* __restrict__ bm1, const float* __restrict__ Wm2,
    const float* __restrict__ bm2, const float* __restrict__ Wm3,
    const float* __restrict__ bm3, float* __restrict__ out) {
  __shared__ float rr[768];
  __shared__ float h1[32];
  __shared__ float h2[8];
  int b = blockIdx.x;
  int tid = threadIdx.x;
  for (int i = tid; i < 768; i += 64) rr[i] = r[(size_t)b * 768 + i];
  __syncthreads();
  if (tid < 32) {
    float s = bm1[tid];
    for (int i = 0; i < 768; ++i) s += rr[i] * Wm1[i * 32 + tid];
    h1[tid] = fmaxf(s, 0.f);
  }
  __syncthreads();
  if (tid < 8) {
    float s = bm2[tid];
    for (int i = 0; i < 32; ++i) s += h1[i] * Wm2[i * 8 + tid];
    h2[tid] = fmaxf(s, 0.f);
  }
  __syncthreads();
  if (tid < 2) {
    float s = bm3[tid];
    for (int i = 0; i < 8; ++i) s += h2[i] * Wm3[i * 2 + tid];
    out[b * 2 + tid] = s;
  }
}

// ---------------------------------------------------------------------------
extern "C" void kernel_launch(void* const* d_in, const int* in_sizes, int n_in,
                              void* d_out, int out_size, void* d_ws, size_t ws_size,
                              hipStream_t stream) {
  const float* x[2]  = {(const float*)d_in[0], (const float*)d_in[3]};
  const float* eat[2] = {(const float*)d_in[1], (const float*)d_in[4]};
  const int*   ei[2] = {(const int*)d_in[2], (const int*)d_in[5]};
  const int N = in_sizes[0] / 128;
  const int E = in_sizes[2] / 2;
  const int Bg = 64;
  const int npg = N / Bg;          // 1000
  const int kq = npg / 2;          // 500

  const float* W1[4] = {(const float*)d_in[9], (const float*)d_in[11],
                        (const float*)d_in[13], (const float*)d_in[15]};
  const float* b1[4] = {(const float*)d_in[10], (const float*)d_in[12],
                        (const float*)d_in[14], (const float*)d_in[16]};
  const float* W2 = (const float*)d_in[17];
  const float* b2 = (const float*)d_in[18];
  const float* W3 = (const float*)d_in[19];
  const float* b3 = (const float*)d_in[20];
  const float* Wsrel  = (const float*)d_in[21];
  const float* bsrel  = (const float*)d_in[22];
  const float* Wsroot = (const float*)d_in[23];
  const float* Wm1 = (const float*)d_in[24];
  const float* bm1 = (const float*)d_in[25];
  const float* Wm2 = (const float*)d_in[26];
  const float* bm2 = (const float*)d_in[27];
  const float* Wm3 = (const float*)d_in[28];
  const float* bm3 = (const float*)d_in[29];
  float* out = (float*)d_out;

  // workspace carve
  char* ws = (char*)d_ws;
  size_t off = 0;
  auto alloc = [&](size_t bytes) -> void* {
    void* p = ws + off;
    off = (off + bytes + 511) & ~(size_t)511;
    return p;
  };
  const size_t nf = (size_t)N * 128 * sizeof(float);
  float* P0 = (float*)alloc(nf);   // S0 / agg2 / agg3
  float* P1 = (float*)alloc(nf);   // S1 / g2
  float* P2 = (float*)alloc(nf);   // S2 / g3
  float* P3 = (float*)alloc(nf);   // S3
  float* P4 = (float*)alloc(nf);   // g1
  float* dinv = (float*)alloc((size_t)5 * N * sizeof(float));
  float* trel = (float*)alloc((size_t)N * sizeof(float));
  float* trot = (float*)alloc((size_t)N * sizeof(float));
  float* sco  = (float*)alloc((size_t)N * sizeof(float));
  int* rowptr = (int*)alloc((size_t)(N + 1) * sizeof(int));
  int* cnt    = (int*)alloc((size_t)N * sizeof(int));
  int* csr    = (int*)alloc((size_t)E * sizeof(int));
  int* csrSrc = (int*)alloc((size_t)E * sizeof(int));
  float4* csrW = (float4*)alloc((size_t)E * sizeof(float4));
  float* csrWO = (float*)alloc((size_t)E * sizeof(float));
  int* bsum   = (int*)alloc(1024);
  float* rbuf = (float*)alloc((size_t)Bg * 768 * sizeof(float));
  if (off > ws_size) return;

  const int nbN = (N + TPB - 1) / TPB;
  const int nbE = (E + TPB - 1) / TPB;
  const int nbGather = N / 8;       // 8000
  const int nbGemm = N / 64;        // 1000

  for (int br = 0; br < 2; ++br) {
    const int* erow = ei[br];
    const int* ecol = ei[br] + E;

    // CSR build (deterministic: sorted segments)
    hipMemsetAsync(cnt, 0, (size_t)N * sizeof(int), stream);
    count_k<<<nbE, TPB, 0, stream>>>(ecol, cnt, E);
    scan1_k<<<nbN, TPB, 0, stream>>>(cnt, rowptr, bsum, N);
    scan2_k<<<1, TPB, 0, stream>>>(bsum, nbN);
    scan3_k<<<nbN, TPB, 0, stream>>>(rowptr, bsum, N, E);
    hipMemsetAsync(cnt, 0, (size_t)N * sizeof(int), stream);
    fill_k<<<nbE, TPB, 0, stream>>>(ecol, rowptr, cnt, csr, E);
    sortadj_k<<<nbN, TPB, 0, stream>>>(rowptr, csr, N);
    deg_k<<<nbN, TPB, 0, stream>>>(rowptr, csr, eat[br], dinv, N);
    eresolve_k<<<nbE, TPB, 0, stream>>>(csr, erow, eat[br], dinv, N, E,
                                        csrSrc, csrW, csrWO);

    // conv1: fused 4-channel aggregate of x -> S0..S3, then fused 4-GEMM -> g1
    gather4_k<<<nbGather, 256, 0, stream>>>(
        (const float4*)x[br], rowptr, csrSrc, csrW, dinv, N,
        (float4*)P0, (float4*)P1, (float4*)P2, (float4*)P3);
    gemm4_k<<<nbGemm, 256, 0, stream>>>(P0, P1, P2, P3,
                                        W1[0], W1[1], W1[2], W1[3],
                                        b1[0], b1[1], b1[2], b1[3], P4, N);

    // conv2: aggregate g1 -> P0, g2 = relu(P0 @ W2 + b2) -> P1
    gather1_k<<<nbGather, 256, 0, stream>>>(
        (const float4*)P4, rowptr, csrSrc, csrWO, dinv + (size_t)4 * N, N,
        (float4*)P0);
    gemm_epi<true><<<nbGemm, 256, 0, stream>>>(P0, W2, b2, P1, N);

    // conv3: aggregate g2 -> P0, g3 = P0 @ W3 + b3 -> P2
    gather1_k<<<nbGather, 256, 0, stream>>>(
        (const float4*)P1, rowptr, csrSrc, csrWO, dinv + (size_t)4 * N, N,
        (float4*)P0);
    gemm_epi<false><<<nbGemm, 256, 0, stream>>>(P0, W3, b3, P2, N);

    // score + top-k pool (g1=P4, g2=P1, g3=P2)
    score_a<<<(N + 3) / 4, 256, 0, stream>>>(P4, P1, P2, Wsrel, Wsroot, trel, trot, N);
    score_b<<<nbN, TPB, 0, stream>>>(rowptr, csrSrc, trel, trot, bsrel, sco, N);
    topk_pool<<<Bg, 512, 0, stream>>>(sco, P4, P1, P2, rbuf, br, npg, kq);
  }

  mlp_k<<<Bg, 64, 0, stream>>>(rbuf, Wm1, bm1, Wm2, bm2, Wm3, bm3, out);
}

// Round 8
// 988.862 us; speedup vs baseline: 1.7903x; 1.7903x over previous
//
#include <hip/hip_runtime.h>
#include <math.h>

// ---------------------------------------------------------------------------
// PGCN twin-branch GCN. fp32. R8 = R4 structure exactly (64x128 tile, kc=64,
// single-buffer, As[64][64]/Ws[64][128] proven-conflict-free layouts), with
// one change: compute64 reads 4 k at a time via aligned b128 on BOTH operands
// (12 LDS issues per 128 FMAs vs 36 in R4). Accumulation order bitwise = R4.
// ---------------------------------------------------------------------------

#define TPB 256

__device__ __forceinline__ int swz_block(int bid, int nb) {
  int per = nb >> 3;
  return (bid & 7) * per + (bid >> 3);
}

__device__ __forceinline__ void f4fma(float4& a, const float4 b, float s) {
  a.x += b.x * s; a.y += b.y * s; a.z += b.z * s; a.w += b.w * s;
}
__device__ __forceinline__ float4 f4s(const float4 a, float s) {
  return make_float4(a.x * s, a.y * s, a.z * s, a.w * s);
}

// ---------------- CSR build ----------------
__global__ __launch_bounds__(TPB) void count_k(const int* __restrict__ col,
                                               int* __restrict__ cnt, int E) {
  int e = blockIdx.x * TPB + threadIdx.x;
  if (e < E) atomicAdd(&cnt[col[e]], 1);
}

__global__ __launch_bounds__(TPB) void scan1_k(const int* __restrict__ cnt,
                                               int* __restrict__ rowptr,
                                               int* __restrict__ bsum, int N) {
  __shared__ int s[TPB];
  int tid = threadIdx.x;
  int gid = blockIdx.x * TPB + tid;
  int v = (gid < N) ? cnt[gid] : 0;
  s[tid] = v;
  __syncthreads();
  for (int o = 1; o < TPB; o <<= 1) {
    int t = (tid >= o) ? s[tid - o] : 0;
    __syncthreads();
    s[tid] += t;
    __syncthreads();
  }
  if (gid < N) rowptr[gid] = s[tid] - v;
  if (tid == TPB - 1) bsum[blockIdx.x] = s[TPB - 1];
}

__global__ __launch_bounds__(TPB) void scan2_k(int* __restrict__ bsum, int nb) {
  __shared__ int s[TPB];
  int tid = threadIdx.x;
  int v = (tid < nb) ? bsum[tid] : 0;
  s[tid] = v;
  __syncthreads();
  for (int o = 1; o < TPB; o <<= 1) {
    int t = (tid >= o) ? s[tid - o] : 0;
    __syncthreads();
    s[tid] += t;
    __syncthreads();
  }
  if (tid < nb) bsum[tid] = s[tid] - v;
}

__global__ __launch_bounds__(TPB) void scan3_k(int* __restrict__ rowptr,
                                               const int* __restrict__ bsum,
                                               int N, int E) {
  int gid = blockIdx.x * TPB + threadIdx.x;
  if (gid < N) rowptr[gid] += bsum[blockIdx.x];
  if (gid == 0) rowptr[N] = E;
}

__global__ __launch_bounds__(TPB) void fill_k(const int* __restrict__ col,
                                              const int* __restrict__ rowptr,
                                              int* __restrict__ fil,
                                              int* __restrict__ csr, int E) {
  int e = blockIdx.x * TPB + threadIdx.x;
  if (e < E) {
    int c = col[e];
    int p = rowptr[c] + atomicAdd(&fil[c], 1);
    csr[p] = e;
  }
}

__global__ __launch_bounds__(TPB) void sortadj_k(const int* __restrict__ rowptr,
                                                 int* __restrict__ csr, int N) {
  int i = blockIdx.x * TPB + threadIdx.x;
  if (i >= N) return;
  int s = rowptr[i], e = rowptr[i + 1];
  for (int a = s + 1; a < e; ++a) {
    int v = csr[a];
    int b = a - 1;
    while (b >= s && csr[b] > v) { csr[b + 1] = csr[b]; --b; }
    csr[b + 1] = v;
  }
}

__global__ __launch_bounds__(TPB) void deg_k(const int* __restrict__ rowptr,
                                             const int* __restrict__ csr,
                                             const float* __restrict__ ea,
                                             float* __restrict__ dinv, int N) {
  int i = blockIdx.x * TPB + threadIdx.x;
  if (i >= N) return;
  int s = rowptr[i], e = rowptr[i + 1];
  float d0 = 1.f, d1 = 1.f, d2 = 1.f, d3 = 1.f;
  for (int j = s; j < e; ++j) {
    int eid = csr[j];
    float4 w = *reinterpret_cast<const float4*>(&ea[(size_t)eid * 4]);
    d0 += w.x; d1 += w.y; d2 += w.z; d3 += w.w;
  }
  float dO = (float)(e - s) + 1.f;
  dinv[0 * N + i] = 1.f / sqrtf(d0);
  dinv[1 * N + i] = 1.f / sqrtf(d1);
  dinv[2 * N + i] = 1.f / sqrtf(d2);
  dinv[3 * N + i] = 1.f / sqrtf(d3);
  dinv[4 * N + i] = 1.f / sqrtf(dO);
}

__global__ __launch_bounds__(TPB) void eresolve_k(
    const int* __restrict__ csr, const int* __restrict__ erow,
    const float* __restrict__ ea, const float* __restrict__ dinv, int N, int E,
    int* __restrict__ csrSrc, float4* __restrict__ csrW,
    float* __restrict__ csrWO) {
  int j = blockIdx.x * TPB + threadIdx.x;
  if (j >= E) return;
  int eid = csr[j];
  int r = erow[eid];
  float4 a = *reinterpret_cast<const float4*>(&ea[(size_t)eid * 4]);
  csrSrc[j] = r;
  csrW[j] = make_float4(a.x * dinv[r], a.y * dinv[N + r], a.z * dinv[2 * N + r],
                        a.w * dinv[3 * N + r]);
  csrWO[j] = dinv[4 * N + r];
}

// ------------- fused 4-channel gather on raw x -> S0..S3 ----------
__global__ __launch_bounds__(256) void gather4_k(
    const float4* __restrict__ X, const int* __restrict__ rowptr,
    const int* __restrict__ csrSrc, const float4* __restrict__ csrW,
    const float* __restrict__ dinv, int N, float4* __restrict__ S0,
    float4* __restrict__ S1, float4* __restrict__ S2, float4* __restrict__ S3) {
  int sb = swz_block(blockIdx.x, gridDim.x);
  int node = sb * 8 + (threadIdx.x >> 5);
  int l = threadIdx.x & 31;
  int s = rowptr[node], e = rowptr[node + 1];
  float d0 = dinv[node], d1 = dinv[N + node], d2 = dinv[2 * N + node],
        d3 = dinv[3 * N + node];
  float4 xs = X[(size_t)node * 32 + l];
  float4 a0 = f4s(xs, d0), a1 = f4s(xs, d1), a2 = f4s(xs, d2), a3 = f4s(xs, d3);
  int j = s;
  for (; j + 3 < e; j += 4) {
    int r0 = csrSrc[j], r1 = csrSrc[j + 1], r2 = csrSrc[j + 2], r3 = csrSrc[j + 3];
    float4 w0 = csrW[j], w1 = csrW[j + 1], w2 = csrW[j + 2], w3 = csrW[j + 3];
    float4 x0 = X[(size_t)r0 * 32 + l];
    float4 x1 = X[(size_t)r1 * 32 + l];
    float4 x2 = X[(size_t)r2 * 32 + l];
    float4 x3 = X[(size_t)r3 * 32 + l];
    f4fma(a0, x0, w0.x); f4fma(a1, x0, w0.y); f4fma(a2, x0, w0.z); f4fma(a3, x0, w0.w);
    f4fma(a0, x1, w1.x); f4fma(a1, x1, w1.y); f4fma(a2, x1, w1.z); f4fma(a3, x1, w1.w);
    f4fma(a0, x2, w2.x); f4fma(a1, x2, w2.y); f4fma(a2, x2, w2.z); f4fma(a3, x2, w2.w);
    f4fma(a0, x3, w3.x); f4fma(a1, x3, w3.y); f4fma(a2, x3, w3.z); f4fma(a3, x3, w3.w);
  }
  for (; j < e; ++j) {
    int r = csrSrc[j];
    float4 w = csrW[j];
    float4 xr = X[(size_t)r * 32 + l];
    f4fma(a0, xr, w.x); f4fma(a1, xr, w.y); f4fma(a2, xr, w.z); f4fma(a3, xr, w.w);
  }
  size_t o = (size_t)node * 32 + l;
  S0[o] = f4s(a0, d0);
  S1[o] = f4s(a1, d1);
  S2[o] = f4s(a2, d2);
  S3[o] = f4s(a3, d3);
}

// ------------- single-channel gather (ones weights) ----------
__global__ __launch_bounds__(256) void gather1_k(
    const float4* __restrict__ X, const int* __restrict__ rowptr,
    const int* __restrict__ csrSrc, const float* __restrict__ csrWO,
    const float* __restrict__ dinvO, int N, float4* __restrict__ Out) {
  int sb = swz_block(blockIdx.x, gridDim.x);
  int node = sb * 8 + (threadIdx.x >> 5);
  int l = threadIdx.x & 31;
  int s = rowptr[node], e = rowptr[node + 1];
  float di = dinvO[node];
  float4 acc = f4s(X[(size_t)node * 32 + l], di);
  int j = s;
  for (; j + 3 < e; j += 4) {
    int r0 = csrSrc[j], r1 = csrSrc[j + 1], r2 = csrSrc[j + 2], r3 = csrSrc[j + 3];
    float w0 = csrWO[j], w1 = csrWO[j + 1], w2 = csrWO[j + 2], w3 = csrWO[j + 3];
    float4 x0 = X[(size_t)r0 * 32 + l];
    float4 x1 = X[(size_t)r1 * 32 + l];
    float4 x2 = X[(size_t)r2 * 32 + l];
    float4 x3 = X[(size_t)r3 * 32 + l];
    f4fma(acc, x0, w0); f4fma(acc, x1, w1); f4fma(acc, x2, w2); f4fma(acc, x3, w3);
  }
  for (; j < e; ++j) {
    f4fma(acc, X[(size_t)csrSrc[j] * 32 + l], csrWO[j]);
  }
  Out[(size_t)node * 32 + l] = f4s(acc, di);
}

// ---------------- GEMM core (64x128 tile, 8 rows x 4 cols per thread) --------
// R4-proven LDS layouts: As[64][64] row-major, Ws[64][128]. New: k-vectorized
// b128 reads on both operands (aligned; A = 2-addr broadcast, B = linear).

__device__ __forceinline__ void stageA(const float* __restrict__ A,
                                       float (*__restrict__ As)[64],
                                       int rowBase, int kc, int tid) {
#pragma unroll
  for (int i = 0; i < 4; ++i) {
    int u = tid + i * 256;
    int r = u >> 4, c4 = u & 15;
    *reinterpret_cast<float4*>(&As[r][c4 * 4]) =
        *reinterpret_cast<const float4*>(
            &A[(size_t)(rowBase + r) * 128 + kc + c4 * 4]);
  }
}

__device__ __forceinline__ void stageW(const float* __restrict__ W,
                                       float (*__restrict__ Ws)[128], int kc,
                                       int tid) {
#pragma unroll
  for (int i = 0; i < 8; ++i) {
    int u = tid + i * 256;
    int r = u >> 5, c4 = u & 31;
    *reinterpret_cast<float4*>(&Ws[r][c4 * 4]) =
        *reinterpret_cast<const float4*>(&W[(size_t)(kc + r) * 128 + c4 * 4]);
  }
}

__device__ __forceinline__ void compute64(const float (*__restrict__ As)[64],
                                          const float (*__restrict__ Ws)[128],
                                          int tx, int ty, float acc[8][4]) {
#pragma unroll 2
  for (int k = 0; k < 64; k += 4) {
    float a[8][4], b[4][4];
#pragma unroll
    for (int j = 0; j < 8; ++j)
      *reinterpret_cast<float4*>(&a[j][0]) =
          *reinterpret_cast<const float4*>(&As[ty * 8 + j][k]);
#pragma unroll
    for (int kk = 0; kk < 4; ++kk)
      *reinterpret_cast<float4*>(&b[kk][0]) =
          *reinterpret_cast<const float4*>(&Ws[k + kk][tx * 4]);
#pragma unroll
    for (int kk = 0; kk < 4; ++kk)
#pragma unroll
      for (int j = 0; j < 8; ++j) {
        acc[j][0] += a[j][kk] * b[kk][0];
        acc[j][1] += a[j][kk] * b[kk][1];
        acc[j][2] += a[j][kk] * b[kk][2];
        acc[j][3] += a[j][kk] * b[kk][3];
      }
  }
}

// C = act(A @ W + bias)
template <bool RELU>
__global__ __launch_bounds__(256) void gemm_epi(const float* __restrict__ A,
                                                const float* __restrict__ Wp,
                                                const float* __restrict__ bias,
                                                float* __restrict__ C, int M) {
  __shared__ float As[64][64];
  __shared__ float Ws[64][128];
  int tid = threadIdx.x;
  int tx = tid & 31;   // cols tx*4 .. +3
  int ty = tid >> 5;   // rows ty*8 .. +7
  int rowBase = blockIdx.x * 64;
  float acc[8][4] = {};
  for (int kc = 0; kc < 128; kc += 64) {
    stageA(A, As, rowBase, kc, tid);
    stageW(Wp, Ws, kc, tid);
    __syncthreads();
    compute64(As, Ws, tx, ty, acc);
    __syncthreads();
  }
  float4 bq = *reinterpret_cast<const float4*>(&bias[tx * 4]);
#pragma unroll
  for (int j = 0; j < 8; ++j) {
    float v0 = acc[j][0] + bq.x, v1 = acc[j][1] + bq.y, v2 = acc[j][2] + bq.z,
          v3 = acc[j][3] + bq.w;
    if (RELU) {
      v0 = fmaxf(v0, 0.f); v1 = fmaxf(v1, 0.f); v2 = fmaxf(v2, 0.f); v3 = fmaxf(v3, 0.f);
    }
    size_t r = (size_t)(rowBase + ty * 8 + j) * 128 + tx * 4;
    *reinterpret_cast<float4*>(&C[r]) = make_float4(v0, v1, v2, v3);
  }
}

// g1 = 0.25 * sum_q relu(S_q @ W_q + b_q)
__global__ __launch_bounds__(256) void gemm4_k(
    const float* __restrict__ S0, const float* __restrict__ S1,
    const float* __restrict__ S2, const float* __restrict__ S3,
    const float* __restrict__ W0, const float* __restrict__ W1,
    const float* __restrict__ W2, const float* __restrict__ W3,
    const float* __restrict__ B0, const float* __restrict__ B1,
    const float* __restrict__ B2, const float* __restrict__ B3,
    float* __restrict__ g1, int M) {
  __shared__ float As[64][64];
  __shared__ float Ws[64][128];
  const float* Sarr[4] = {S0, S1, S2, S3};
  const float* Warr[4] = {W0, W1, W2, W3};
  const float* Barr[4] = {B0, B1, B2, B3};
  int tid = threadIdx.x;
  int tx = tid & 31;
  int ty = tid >> 5;
  int rowBase = blockIdx.x * 64;
  float facc[8][4] = {};
#pragma unroll 1
  for (int q = 0; q < 4; ++q) {
    const float* A = Sarr[q];
    const float* Wp = Warr[q];
    float acc[8][4] = {};
    for (int kc = 0; kc < 128; kc += 64) {
      stageA(A, As, rowBase, kc, tid);
      stageW(Wp, Ws, kc, tid);
      __syncthreads();
      compute64(As, Ws, tx, ty, acc);
      __syncthreads();
    }
    float4 bq = *reinterpret_cast<const float4*>(&Barr[q][tx * 4]);
#pragma unroll
    for (int j = 0; j < 8; ++j) {
      facc[j][0] += fmaxf(acc[j][0] + bq.x, 0.f) * 0.25f;
      facc[j][1] += fmaxf(acc[j][1] + bq.y, 0.f) * 0.25f;
      facc[j][2] += fmaxf(acc[j][2] + bq.z, 0.f) * 0.25f;
      facc[j][3] += fmaxf(acc[j][3] + bq.w, 0.f) * 0.25f;
    }
  }
#pragma unroll
  for (int j = 0; j < 8; ++j) {
    size_t r = (size_t)(rowBase + ty * 8 + j) * 128 + tx * 4;
    *reinterpret_cast<float4*>(&g1[r]) =
        make_float4(facc[j][0], facc[j][1], facc[j][2], facc[j][3]);
  }
}

// ------------- score -------------
__global__ __launch_bounds__(256) void score_a(
    const float* __restrict__ g1, const float* __restrict__ g2,
    const float* __restrict__ g3, const float* __restrict__ Wrel,
    const float* __restrict__ Wroot, float* __restrict__ trel,
    float* __restrict__ troot, int N) {
  int wave = threadIdx.x >> 6;
  int lane = threadIdx.x & 63;
  int node = blockIdx.x * 4 + wave;
  if (node >= N) return;
  float sr = 0.f, so = 0.f;
#pragma unroll
  for (int t = 0; t < 2; ++t) {
    int f = lane + t * 64;
    float v1 = g1[(size_t)node * 128 + f];
    float v2 = g2[(size_t)node * 128 + f];
    float v3 = g3[(size_t)node * 128 + f];
    sr += v1 * Wrel[f] + v2 * Wrel[128 + f] + v3 * Wrel[256 + f];
    so += v1 * Wroot[f] + v2 * Wroot[128 + f] + v3 * Wroot[256 + f];
  }
  for (int off = 32; off; off >>= 1) {
    sr += __shfl_down(sr, off);
    so += __shfl_down(so, off);
  }
  if (lane == 0) { trel[node] = sr; troot[node] = so; }
}

__global__ __launch_bounds__(TPB) void score_b(
    const int* __restrict__ rowptr, const int* __restrict__ csrSrc,
    const float* __restrict__ trel, const float* __restrict__ troot,
    const float* __restrict__ bs, float* __restrict__ score, int N) {
  int i = blockIdx.x * TPB + threadIdx.x;
  if (i >= N) return;
  float sc = bs[0] + troot[i];
  int s = rowptr[i], e = rowptr[i + 1];
  for (int j = s; j < e; ++j) sc += trel[csrSrc[j]];
  score[i] = sc;
}

// ------------- per-graph top-k (bitonic) + tanh-weighted mean pool -------------
__global__ __launch_bounds__(512) void topk_pool(
    const float* __restrict__ score, const float* __restrict__ g1,
    const float* __restrict__ g2, const float* __restrict__ g3,
    float* __restrict__ r, int half, int npg, int k) {
  __shared__ float key[1024];
  __shared__ int idx[1024];
  __shared__ float wts[512];
  int b = blockIdx.x;
  int tid = threadIdx.x;
  int base = b * npg;
  for (int i = tid; i < 1024; i += 512) {
    key[i] = (i < npg) ? score[base + i] : -3.0e38f;
    idx[i] = i;
  }
  __syncthreads();
  for (int kk = 2; kk <= 1024; kk <<= 1) {
    for (int j = kk >> 1; j > 0; j >>= 1) {
      for (int i = tid; i < 1024; i += 512) {
        int ixj = i ^ j;
        if (ixj > i) {
          bool desc = ((i & kk) == 0);
          float ki = key[i], kj = key[ixj];
          bool sw = desc ? (ki < kj) : (ki > kj);
          if (sw) {
            key[i] = kj; key[ixj] = ki;
            int t = idx[i]; idx[i] = idx[ixj]; idx[ixj] = t;
          }
        }
      }
      __syncthreads();
    }
  }
  if (tid < k) wts[tid] = tanhf(key[tid]);
  __syncthreads();
  if (tid < 384) {
    const float* gp = (tid < 128) ? g1 : ((tid < 256) ? g2 : g3);
    int fo = tid & 127;
    float acc = 0.f;
    for (int j = 0; j < k; ++j) {
      int n = base + idx[j];
      acc += wts[j] * gp[(size_t)n * 128 + fo];
    }
    r[(size_t)b * 768 + half * 384 + tid] = acc / (float)k;
  }
}

// ------------- MLP 768 -> 32 -> 8 -> 2 -------------
__global__ __launch_bounds__(64) void mlp_k(
    const float* __restrict__ r, const float* __restrict__ Wm1,
    const float* __restrict__ bm1, const float* __restrict__ Wm2,
    const float* __restrict__ bm2, const float* __restrict__ Wm3,
    const float* __restrict__ bm3, float* __restrict__ out) {
  __shared__ float rr[768];
  __shared__ float h1[32];
  __shared__ float h2[8];
  int b = blockIdx.x;
  int tid = threadIdx.x;
  for (int i = tid; i < 768; i += 64) rr[i] = r[(size_t)b * 768 + i];
  __syncthreads();
  if (tid < 32) {
    float s = bm1[tid];
    for (int i = 0; i < 768; ++i) s += rr[i] * Wm1[i * 32 + tid];
    h1[tid] = fmaxf(s, 0.f);
  }
  __syncthreads();
  if (tid < 8) {
    float s = bm2[tid];
    for (int i = 0; i < 32; ++i) s += h1[i] * Wm2[i * 8 + tid];
    h2[tid] = fmaxf(s, 0.f);
  }
  __syncthreads();
  if (tid < 2) {
    float s = bm3[tid];
    for (int i = 0; i < 8; ++i) s += h2[i] * Wm3[i * 2 + tid];
    out[b * 2 + tid] = s;
  }
}

// ---------------------------------------------------------------------------
extern "C" void kernel_launch(void* const* d_in, const int* in_sizes, int n_in,
                              void* d_out, int out_size, void* d_ws, size_t ws_size,
                              hipStream_t stream) {
  const float* x[2]  = {(const float*)d_in[0], (const float*)d_in[3]};
  const float* eat[2] = {(const float*)d_in[1], (const float*)d_in[4]};
  const int*   ei[2] = {(const int*)d_in[2], (const int*)d_in[5]};
  const int N = in_sizes[0] / 128;
  const int E = in_sizes[2] / 2;
  const int Bg = 64;
  const int npg = N / Bg;          // 1000
  const int kq = npg / 2;          // 500

  const float* W1[4] = {(const float*)d_in[9], (const float*)d_in[11],
                        (const float*)d_in[13], (const float*)d_in[15]};
  const float* b1[4] = {(const float*)d_in[10], (const float*)d_in[12],
                        (const float*)d_in[14], (const float*)d_in[16]};
  const float* W2 = (const float*)d_in[17];
  const float* b2 = (const float*)d_in[18];
  const float* W3 = (const float*)d_in[19];
  const float* b3 = (const float*)d_in[20];
  const float* Wsrel  = (const float*)d_in[21];
  const float* bsrel  = (const float*)d_in[22];
  const float* Wsroot = (const float*)d_in[23];
  const float* Wm1 = (const float*)d_in[24];
  const float* bm1 = (const float*)d_in[25];
  const float* Wm2 = (const float*)d_in[26];
  const float* bm2 = (const float*)d_in[27];
  const float* Wm3 = (const float*)d_in[28];
  const float* bm3 = (const float*)d_in[29];
  float* out = (float*)d_out;

  // workspace carve
  char* ws = (char*)d_ws;
  size_t off = 0;
  auto alloc = [&](size_t bytes) -> void* {
    void* p = ws + off;
    off = (off + bytes + 511) & ~(size_t)511;
    return p;
  };
  const size_t nf = (size_t)N * 128 * sizeof(float);
  float* P0 = (float*)alloc(nf);   // S0 / agg2 / agg3
  float* P1 = (float*)alloc(nf);   // S1 / g2
  float* P2 = (float*)alloc(nf);   // S2 / g3
  float* P3 = (float*)alloc(nf);   // S3
  float* P4 = (float*)alloc(nf);   // g1
  float* dinv = (float*)alloc((size_t)5 * N * sizeof(float));
  float* trel = (float*)alloc((size_t)N * sizeof(float));
  float* trot = (float*)alloc((size_t)N * sizeof(float));
  float* sco  = (float*)alloc((size_t)N * sizeof(float));
  int* rowptr = (int*)alloc((size_t)(N + 1) * sizeof(int));
  int* cnt    = (int*)alloc((size_t)N * sizeof(int));
  int* csr    = (int*)alloc((size_t)E * sizeof(int));
  int* csrSrc = (int*)alloc((size_t)E * sizeof(int));
  float4* csrW = (float4*)alloc((size_t)E * sizeof(float4));
  float* csrWO = (float*)alloc((size_t)E * sizeof(float));
  int* bsum   = (int*)alloc(1024);
  float* rbuf = (float*)alloc((size_t)Bg * 768 * sizeof(float));
  if (off > ws_size) return;

  const int nbN = (N + TPB - 1) / TPB;
  const int nbE = (E + TPB - 1) / TPB;
  const int nbGather = N / 8;       // 8000
  const int nbGemm = N / 64;        // 1000

  for (int br = 0; br < 2; ++br) {
    const int* erow = ei[br];
    const int* ecol = ei[br] + E;

    // CSR build (deterministic: sorted segments)
    hipMemsetAsync(cnt, 0, (size_t)N * sizeof(int), stream);
    count_k<<<nbE, TPB, 0, stream>>>(ecol, cnt, E);
    scan1_k<<<nbN, TPB, 0, stream>>>(cnt, rowptr, bsum, N);
    scan2_k<<<1, TPB, 0, stream>>>(bsum, nbN);
    scan3_k<<<nbN, TPB, 0, stream>>>(rowptr, bsum, N, E);
    hipMemsetAsync(cnt, 0, (size_t)N * sizeof(int), stream);
    fill_k<<<nbE, TPB, 0, stream>>>(ecol, rowptr, cnt, csr, E);
    sortadj_k<<<nbN, TPB, 0, stream>>>(rowptr, csr, N);
    deg_k<<<nbN, TPB, 0, stream>>>(rowptr, csr, eat[br], dinv, N);
    eresolve_k<<<nbE, TPB, 0, stream>>>(csr, erow, eat[br], dinv, N, E,
                                        csrSrc, csrW, csrWO);

    // conv1: fused 4-channel aggregate of x -> S0..S3, then fused 4-GEMM -> g1
    gather4_k<<<nbGather, 256, 0, stream>>>(
        (const float4*)x[br], rowptr, csrSrc, csrW, dinv, N,
        (float4*)P0, (float4*)P1, (float4*)P2, (float4*)P3);
    gemm4_k<<<nbGemm, 256, 0, stream>>>(P0, P1, P2, P3,
                                        W1[0], W1[1], W1[2], W1[3],
                                        b1[0], b1[1], b1[2], b1[3], P4, N);

    // conv2: aggregate g1 -> P0, g2 = relu(P0 @ W2 + b2) -> P1
    gather1_k<<<nbGather, 256, 0, stream>>>(
        (const float4*)P4, rowptr, csrSrc, csrWO, dinv + (size_t)4 * N, N,
        (float4*)P0);
    gemm_epi<true><<<nbGemm, 256, 0, stream>>>(P0, W2, b2, P1, N);

    // conv3: aggregate g2 -> P0, g3 = P0 @ W3 + b3 -> P2
    gather1_k<<<nbGather, 256, 0, stream>>>(
        (const float4*)P1, rowptr, csrSrc, csrWO, dinv + (size_t)4 * N, N,
        (float4*)P0);
    gemm_epi<false><<<nbGemm, 256, 0, stream>>>(P0, W3, b3, P2, N);

    // score + top-k pool (g1=P4, g2=P1, g3=P2)
    score_a<<<(N + 3) / 4, 256, 0, stream>>>(P4, P1, P2, Wsrel, Wsroot, trel, trot, N);
    score_b<<<nbN, TPB, 0, stream>>>(rowptr, csrSrc, trel, trot, bsrel, sco, N);
    topk_pool<<<Bg, 512, 0, stream>>>(sco, P4, P1, P2, rbuf, br, npg, kq);
  }

  mlp_k<<<Bg, 64, 0, stream>>>(rbuf, Wm1, bm1, Wm2, bm2, Wm3, bm3, out);
}

// Round 9
// 975.781 us; speedup vs baseline: 1.8143x; 1.0134x over previous
//
#include <hip/hip_runtime.h>
#include <math.h>

// ---------------------------------------------------------------------------
// PGCN twin-branch GCN. fp32. R9: GEMM reverted to exact R4 code (proven
// 128us/0-conflict). New: conv2/conv3 fused gather+GEMM kernel (fconv_k) —
// gather 64 rows into LDS, then R4 GEMM loop; 2 blocks/CU overlap gather
// (memory) with GEMM (VALU) across blocks. Bitwise-identical accumulation
// order to R4 everywhere (top-k stable).
// ---------------------------------------------------------------------------

#define TPB 256

__device__ __forceinline__ int swz_block(int bid, int nb) {
  int per = nb >> 3;
  return (bid & 7) * per + (bid >> 3);
}

__device__ __forceinline__ void f4fma(float4& a, const float4 b, float s) {
  a.x += b.x * s; a.y += b.y * s; a.z += b.z * s; a.w += b.w * s;
}
__device__ __forceinline__ float4 f4s(const float4 a, float s) {
  return make_float4(a.x * s, a.y * s, a.z * s, a.w * s);
}

// ---------------- CSR build ----------------
__global__ __launch_bounds__(TPB) void count_k(const int* __restrict__ col,
                                               int* __restrict__ cnt, int E) {
  int e = blockIdx.x * TPB + threadIdx.x;
  if (e < E) atomicAdd(&cnt[col[e]], 1);
}

__global__ __launch_bounds__(TPB) void scan1_k(const int* __restrict__ cnt,
                                               int* __restrict__ rowptr,
                                               int* __restrict__ bsum, int N) {
  __shared__ int s[TPB];
  int tid = threadIdx.x;
  int gid = blockIdx.x * TPB + tid;
  int v = (gid < N) ? cnt[gid] : 0;
  s[tid] = v;
  __syncthreads();
  for (int o = 1; o < TPB; o <<= 1) {
    int t = (tid >= o) ? s[tid - o] : 0;
    __syncthreads();
    s[tid] += t;
    __syncthreads();
  }
  if (gid < N) rowptr[gid] = s[tid] - v;
  if (tid == TPB - 1) bsum[blockIdx.x] = s[TPB - 1];
}

__global__ __launch_bounds__(TPB) void scan2_k(int* __restrict__ bsum, int nb) {
  __shared__ int s[TPB];
  int tid = threadIdx.x;
  int v = (tid < nb) ? bsum[tid] : 0;
  s[tid] = v;
  __syncthreads();
  for (int o = 1; o < TPB; o <<= 1) {
    int t = (tid >= o) ? s[tid - o] : 0;
    __syncthreads();
    s[tid] += t;
    __syncthreads();
  }
  if (tid < nb) bsum[tid] = s[tid] - v;
}

__global__ __launch_bounds__(TPB) void scan3_k(int* __restrict__ rowptr,
                                               const int* __restrict__ bsum,
                                               int N, int E) {
  int gid = blockIdx.x * TPB + threadIdx.x;
  if (gid < N) rowptr[gid] += bsum[blockIdx.x];
  if (gid == 0) rowptr[N] = E;
}

__global__ __launch_bounds__(TPB) void fill_k(const int* __restrict__ col,
                                              const int* __restrict__ rowptr,
                                              int* __restrict__ fil,
                                              int* __restrict__ csr, int E) {
  int e = blockIdx.x * TPB + threadIdx.x;
  if (e < E) {
    int c = col[e];
    int p = rowptr[c] + atomicAdd(&fil[c], 1);
    csr[p] = e;
  }
}

__global__ __launch_bounds__(TPB) void sortadj_k(const int* __restrict__ rowptr,
                                                 int* __restrict__ csr, int N) {
  int i = blockIdx.x * TPB + threadIdx.x;
  if (i >= N) return;
  int s = rowptr[i], e = rowptr[i + 1];
  for (int a = s + 1; a < e; ++a) {
    int v = csr[a];
    int b = a - 1;
    while (b >= s && csr[b] > v) { csr[b + 1] = csr[b]; --b; }
    csr[b + 1] = v;
  }
}

__global__ __launch_bounds__(TPB) void deg_k(const int* __restrict__ rowptr,
                                             const int* __restrict__ csr,
                                             const float* __restrict__ ea,
                                             float* __restrict__ dinv, int N) {
  int i = blockIdx.x * TPB + threadIdx.x;
  if (i >= N) return;
  int s = rowptr[i], e = rowptr[i + 1];
  float d0 = 1.f, d1 = 1.f, d2 = 1.f, d3 = 1.f;
  for (int j = s; j < e; ++j) {
    int eid = csr[j];
    float4 w = *reinterpret_cast<const float4*>(&ea[(size_t)eid * 4]);
    d0 += w.x; d1 += w.y; d2 += w.z; d3 += w.w;
  }
  float dO = (float)(e - s) + 1.f;
  dinv[0 * N + i] = 1.f / sqrtf(d0);
  dinv[1 * N + i] = 1.f / sqrtf(d1);
  dinv[2 * N + i] = 1.f / sqrtf(d2);
  dinv[3 * N + i] = 1.f / sqrtf(d3);
  dinv[4 * N + i] = 1.f / sqrtf(dO);
}

__global__ __launch_bounds__(TPB) void eresolve_k(
    const int* __restrict__ csr, const int* __restrict__ erow,
    const float* __restrict__ ea, const float* __restrict__ dinv, int N, int E,
    int* __restrict__ csrSrc, float4* __restrict__ csrW,
    float* __restrict__ csrWO) {
  int j = blockIdx.x * TPB + threadIdx.x;
  if (j >= E) return;
  int eid = csr[j];
  int r = erow[eid];
  float4 a = *reinterpret_cast<const float4*>(&ea[(size_t)eid * 4]);
  csrSrc[j] = r;
  csrW[j] = make_float4(a.x * dinv[r], a.y * dinv[N + r], a.z * dinv[2 * N + r],
                        a.w * dinv[3 * N + r]);
  csrWO[j] = dinv[4 * N + r];
}

// ------------- fused 4-channel gather on raw x -> S0..S3 ----------
__global__ __launch_bounds__(256) void gather4_k(
    const float4* __restrict__ X, const int* __restrict__ rowptr,
    const int* __restrict__ csrSrc, const float4* __restrict__ csrW,
    const float* __restrict__ dinv, int N, float4* __restrict__ S0,
    float4* __restrict__ S1, float4* __restrict__ S2, float4* __restrict__ S3) {
  int sb = swz_block(blockIdx.x, gridDim.x);
  int node = sb * 8 + (threadIdx.x >> 5);
  int l = threadIdx.x & 31;
  int s = rowptr[node], e = rowptr[node + 1];
  float d0 = dinv[node], d1 = dinv[N + node], d2 = dinv[2 * N + node],
        d3 = dinv[3 * N + node];
  float4 xs = X[(size_t)node * 32 + l];
  float4 a0 = f4s(xs, d0), a1 = f4s(xs, d1), a2 = f4s(xs, d2), a3 = f4s(xs, d3);
  int j = s;
  for (; j + 3 < e; j += 4) {
    int r0 = csrSrc[j], r1 = csrSrc[j + 1], r2 = csrSrc[j + 2], r3 = csrSrc[j + 3];
    float4 w0 = csrW[j], w1 = csrW[j + 1], w2 = csrW[j + 2], w3 = csrW[j + 3];
    float4 x0 = X[(size_t)r0 * 32 + l];
    float4 x1 = X[(size_t)r1 * 32 + l];
    float4 x2 = X[(size_t)r2 * 32 + l];
    float4 x3 = X[(size_t)r3 * 32 + l];
    f4fma(a0, x0, w0.x); f4fma(a1, x0, w0.y); f4fma(a2, x0, w0.z); f4fma(a3, x0, w0.w);
    f4fma(a0, x1, w1.x); f4fma(a1, x1, w1.y); f4fma(a2, x1, w1.z); f4fma(a3, x1, w1.w);
    f4fma(a0, x2, w2.x); f4fma(a1, x2, w2.y); f4fma(a2, x2, w2.z); f4fma(a3, x2, w2.w);
    f4fma(a0, x3, w3.x); f4fma(a1, x3, w3.y); f4fma(a2, x3, w3.z); f4fma(a3, x3, w3.w);
  }
  for (; j < e; ++j) {
    int r = csrSrc[j];
    float4 w = csrW[j];
    float4 xr = X[(size_t)r * 32 + l];
    f4fma(a0, xr, w.x); f4fma(a1, xr, w.y); f4fma(a2, xr, w.z); f4fma(a3, xr, w.w);
  }
  size_t o = (size_t)node * 32 + l;
  S0[o] = f4s(a0, d0);
  S1[o] = f4s(a1, d1);
  S2[o] = f4s(a2, d2);
  S3[o] = f4s(a3, d3);
}

// ---------------- fused conv: gather 64 rows into LDS + R4 GEMM --------------
template <bool RELU>
__global__ __launch_bounds__(256) void fconv_k(
    const float4* __restrict__ X, const int* __restrict__ rowptr,
    const int* __restrict__ csrSrc, const float* __restrict__ csrWO,
    const float* __restrict__ dinvO, const float* __restrict__ Wp,
    const float* __restrict__ bias, float* __restrict__ C, int N) {
  __shared__ float As[64][128];   // aggregated rows (full K), 32 KB
  __shared__ float Ws[64][128];   // W chunk, 32 KB
  int tid = threadIdx.x;
  int sb = swz_block(blockIdx.x, gridDim.x);
  int rowBase = sb * 64;
  int l = tid & 31;

  // Phase 1: gather aggregated rows into As (op order identical to gather1)
  for (int g = tid >> 5; g < 64; g += 8) {
    int node = rowBase + g;
    int s = rowptr[node], e = rowptr[node + 1];
    float di = dinvO[node];
    float4 acc = f4s(X[(size_t)node * 32 + l], di);
    int j = s;
    for (; j + 3 < e; j += 4) {
      int r0 = csrSrc[j], r1 = csrSrc[j + 1], r2 = csrSrc[j + 2], r3 = csrSrc[j + 3];
      float w0 = csrWO[j], w1 = csrWO[j + 1], w2 = csrWO[j + 2], w3 = csrWO[j + 3];
      float4 x0 = X[(size_t)r0 * 32 + l];
      float4 x1 = X[(size_t)r1 * 32 + l];
      float4 x2 = X[(size_t)r2 * 32 + l];
      float4 x3 = X[(size_t)r3 * 32 + l];
      f4fma(acc, x0, w0); f4fma(acc, x1, w1); f4fma(acc, x2, w2); f4fma(acc, x3, w3);
    }
    for (; j < e; ++j) {
      f4fma(acc, X[(size_t)csrSrc[j] * 32 + l], csrWO[j]);
    }
    *reinterpret_cast<float4*>(&As[g][l * 4]) = f4s(acc, di);
  }
  __syncthreads();

  // Phase 2: R4 GEMM loop on As (broadcast reads; Ws staging = R4 pattern)
  int tx = tid & 31;   // cols tx*4 .. +3
  int ty = tid >> 5;   // rows ty*8 .. +7
  float acc[8][4] = {};
  for (int kc = 0; kc < 128; kc += 64) {
#pragma unroll
    for (int i = 0; i < 8; ++i) {
      int u = tid + i * 256;
      int r = u >> 5, c4 = u & 31;
      *reinterpret_cast<float4*>(&Ws[r][c4 * 4]) =
          *reinterpret_cast<const float4*>(&Wp[(size_t)(kc + r) * 128 + c4 * 4]);
    }
    __syncthreads();
#pragma unroll 4
    for (int k = 0; k < 64; ++k) {
      float b0[4];
      *reinterpret_cast<float4*>(b0) = *reinterpret_cast<const float4*>(&Ws[k][tx * 4]);
#pragma unroll
      for (int j = 0; j < 8; ++j) {
        float a = As[ty * 8 + j][kc + k];
        acc[j][0] += a * b0[0];
        acc[j][1] += a * b0[1];
        acc[j][2] += a * b0[2];
        acc[j][3] += a * b0[3];
      }
    }
    __syncthreads();
  }
  float4 bq = *reinterpret_cast<const float4*>(&bias[tx * 4]);
#pragma unroll
  for (int j = 0; j < 8; ++j) {
    float v0 = acc[j][0] + bq.x, v1 = acc[j][1] + bq.y, v2 = acc[j][2] + bq.z,
          v3 = acc[j][3] + bq.w;
    if (RELU) {
      v0 = fmaxf(v0, 0.f); v1 = fmaxf(v1, 0.f); v2 = fmaxf(v2, 0.f); v3 = fmaxf(v3, 0.f);
    }
    size_t r = (size_t)(rowBase + ty * 8 + j) * 128 + tx * 4;
    *reinterpret_cast<float4*>(&C[r]) = make_float4(v0, v1, v2, v3);
  }
}

// ---------------- gemm4 (exact R4): g1 = 0.25 * sum_q relu(S_q @ W_q + b_q) ---
__global__ __launch_bounds__(256) void gemm4_k(
    const float* __restrict__ S0, const float* __restrict__ S1,
    const float* __restrict__ S2, const float* __restrict__ S3,
    const float* __restrict__ W0, const float* __restrict__ W1,
    const float* __restrict__ W2, const float* __restrict__ W3,
    const float* __restrict__ B0, const float* __restrict__ B1,
    const float* __restrict__ B2, const float* __restrict__ B3,
    float* __restrict__ g1, int M) {
  __shared__ float As[64][64];
  __shared__ float Ws[64][128];
  const float* Sarr[4] = {S0, S1, S2, S3};
  const float* Warr[4] = {W0, W1, W2, W3};
  const float* Barr[4] = {B0, B1, B2, B3};
  int tid = threadIdx.x;
  int tx = tid & 31;
  int ty = tid >> 5;
  int rowBase = blockIdx.x * 64;
  float facc[8][4] = {};
#pragma unroll
  for (int q = 0; q < 4; ++q) {
    const float* A = Sarr[q];
    const float* W = Warr[q];
    float acc[8][4] = {};
    for (int kc = 0; kc < 128; kc += 64) {
#pragma unroll
      for (int i = 0; i < 4; ++i) {
        int idx = tid + i * 256;
        int r = idx >> 4;
        int c4 = idx & 15;
        *reinterpret_cast<float4*>(&As[r][c4 * 4]) =
            *reinterpret_cast<const float4*>(&A[(size_t)(rowBase + r) * 128 + kc + c4 * 4]);
      }
#pragma unroll
      for (int i = 0; i < 8; ++i) {
        int idx = tid + i * 256;
        int r = idx >> 5;
        int c4 = idx & 31;
        *reinterpret_cast<float4*>(&Ws[r][c4 * 4]) =
            *reinterpret_cast<const float4*>(&W[(size_t)(kc + r) * 128 + c4 * 4]);
      }
      __syncthreads();
#pragma unroll 4
      for (int k = 0; k < 64; ++k) {
        float b0[4];
        *reinterpret_cast<float4*>(b0) = *reinterpret_cast<const float4*>(&Ws[k][tx * 4]);
#pragma unroll
        for (int j = 0; j < 8; ++j) {
          float a = As[ty * 8 + j][k];
          acc[j][0] += a * b0[0];
          acc[j][1] += a * b0[1];
          acc[j][2] += a * b0[2];
          acc[j][3] += a * b0[3];
        }
      }
      __syncthreads();
    }
    float4 bq = *reinterpret_cast<const float4*>(&Barr[q][tx * 4]);
#pragma unroll
    for (int j = 0; j < 8; ++j) {
      facc[j][0] += fmaxf(acc[j][0] + bq.x, 0.f) * 0.25f;
      facc[j][1] += fmaxf(acc[j][1] + bq.y, 0.f) * 0.25f;
      facc[j][2] += fmaxf(acc[j][2] + bq.z, 0.f) * 0.25f;
      facc[j][3] += fmaxf(acc[j][3] + bq.w, 0.f) * 0.25f;
    }
  }
#pragma unroll
  for (int j = 0; j < 8; ++j) {
    size_t r = (size_t)(rowBase + ty * 8 + j) * 128 + tx * 4;
    *reinterpret_cast<float4*>(&g1[r]) =
        make_float4(facc[j][0], facc[j][1], facc[j][2], facc[j][3]);
  }
}

// ------------- score -------------
__global__ __launch_bounds__(256) void score_a(
    const float* __restrict__ g1, const float* __restrict__ g2,
    const float* __restrict__ g3, const float* __restrict__ Wrel,
    const float* __restrict__ Wroot, float* __restrict__ trel,
    float* __restrict__ troot, int N) {
  int wave = threadIdx.x >> 6;
  int lane = threadIdx.x & 63;
  int node = blockIdx.x * 4 + wave;
  if (node >= N) return;
  float sr = 0.f, so = 0.f;
#pragma unroll
  for (int t = 0; t < 2; ++t) {
    int f = lane + t * 64;
    float v1 = g1[(size_t)node * 128 + f];
    float v2 = g2[(size_t)node * 128 + f];
    float v3 = g3[(size_t)node * 128 + f];
    sr += v1 * Wrel[f] + v2 * Wrel[128 + f] + v3 * Wrel[256 + f];
    so += v1 * Wroot[f] + v2 * Wroot[128 + f] + v3 * Wroot[256 + f];
  }
  for (int off = 32; off; off >>= 1) {
    sr += __shfl_down(sr, off);
    so += __shfl_down(so, off);
  }
  if (lane == 0) { trel[node] = sr; troot[node] = so; }
}

__global__ __launch_bounds__(TPB) void score_b(
    const int* __restrict__ rowptr, const int* __restrict__ csrSrc,
    const float* __restrict__ trel, const float* __restrict__ troot,
    const float* __restrict__ bs, float* __restrict__ score, int N) {
  int i = blockIdx.x * TPB + threadIdx.x;
  if (i >= N) return;
  float sc = bs[0] + troot[i];
  int s = rowptr[i], e = rowptr[i + 1];
  for (int j = s; j < e; ++j) sc += trel[csrSrc[j]];
  score[i] = sc;
}

// ------------- per-graph top-k (bitonic) + tanh-weighted mean pool -------------
__global__ __launch_bounds__(512) void topk_pool(
    const float* __restrict__ score, const float* __restrict__ g1,
    const float* __restrict__ g2, const float* __restrict__ g3,
    float* __restrict__ r, int half, int npg, int k) {
  __shared__ float key[1024];
  __shared__ int idx[1024];
  __shared__ float wts[512];
  int b = blockIdx.x;
  int tid = threadIdx.x;
  int base = b * npg;
  for (int i = tid; i < 1024; i += 512) {
    key[i] = (i < npg) ? score[base + i] : -3.0e38f;
    idx[i] = i;
  }
  __syncthreads();
  for (int kk = 2; kk <= 1024; kk <<= 1) {
    for (int j = kk >> 1; j > 0; j >>= 1) {
      for (int i = tid; i < 1024; i += 512) {
        int ixj = i ^ j;
        if (ixj > i) {
          bool desc = ((i & kk) == 0);
          float ki = key[i], kj = key[ixj];
          bool sw = desc ? (ki < kj) : (ki > kj);
          if (sw) {
            key[i] = kj; key[ixj] = ki;
            int t = idx[i]; idx[i] = idx[ixj]; idx[ixj] = t;
          }
        }
      }
      __syncthreads();
    }
  }
  if (tid < k) wts[tid] = tanhf(key[tid]);
  __syncthreads();
  if (tid < 384) {
    const float* gp = (tid < 128) ? g1 : ((tid < 256) ? g2 : g3);
    int fo = tid & 127;
    float acc = 0.f;
    for (int j = 0; j < k; ++j) {
      int n = base + idx[j];
      acc += wts[j] * gp[(size_t)n * 128 + fo];
    }
    r[(size_t)b * 768 + half * 384 + tid] = acc / (float)k;
  }
}

// ------------- MLP 768 -> 32 -> 8 -> 2 -------------
__global__ __launch_bounds__(64) void mlp_k(
    const float* __restrict__ r, const float* __restrict__ Wm1,
    const float* __restrict__ bm1, const float* __restrict__ Wm2,
    const float* __restrict__ bm2, const float* __restrict__ Wm3,
    const float* __restrict__ bm3, float* __restrict__ out) {
  __shared__ float rr[768];
  __shared__ float h1[32];
  __shared__ float h2[8];
  int b = blockIdx.x;
  int tid = threadIdx.x;
  for (int i = tid; i < 768; i += 64) rr[i] = r[(size_t)b * 768 + i];
  __syncthreads();
  if (tid < 32) {
    float s = bm1[tid];
    for (int i = 0; i < 768; ++i) s += rr[i] * Wm1[i * 32 + tid];
    h1[tid] = fmaxf(s, 0.f);
  }
  __syncthreads();
  if (tid < 8) {
    float s = bm2[tid];
    for (int i = 0; i < 32; ++i) s += h1[i] * Wm2[i * 8 + tid];
    h2[tid] = fmaxf(s, 0.f);
  }
  __syncthreads();
  if (tid < 2) {
    float s = bm3[tid];
    for (int i = 0; i < 8; ++i) s += h2[i] * Wm3[i * 2 + tid];
    out[b * 2 + tid] = s;
  }
}

// ---------------------------------------------------------------------------
extern "C" void kernel_launch(void* const* d_in, const int* in_sizes, int n_in,
                              void* d_out, int out_size, void* d_ws, size_t ws_size,
                              hipStream_t stream) {
  const float* x[2]  = {(const float*)d_in[0], (const float*)d_in[3]};
  const float* eat[2] = {(const float*)d_in[1], (const float*)d_in[4]};
  const int*   ei[2] = {(const int*)d_in[2], (const int*)d_in[5]};
  const int N = in_sizes[0] / 128;
  const int E = in_sizes[2] / 2;
  const int Bg = 64;
  const int npg = N / Bg;          // 1000
  const int kq = npg / 2;          // 500

  const float* W1[4] = {(const float*)d_in[9], (const float*)d_in[11],
                        (const float*)d_in[13], (const float*)d_in[15]};
  const float* b1[4] = {(const float*)d_in[10], (const float*)d_in[12],
                        (const float*)d_in[14], (const float*)d_in[16]};
  const float* W2 = (const float*)d_in[17];
  const float* b2 = (const float*)d_in[18];
  const float* W3 = (const float*)d_in[19];
  const float* b3 = (const float*)d_in[20];
  const float* Wsrel  = (const float*)d_in[21];
  const float* bsrel  = (const float*)d_in[22];
  const float* Wsroot = (const float*)d_in[23];
  const float* Wm1 = (const float*)d_in[24];
  const float* bm1 = (const float*)d_in[25];
  const float* Wm2 = (const float*)d_in[26];
  const float* bm2 = (const float*)d_in[27];
  const float* Wm3 = (const float*)d_in[28];
  const float* bm3 = (const float*)d_in[29];
  float* out = (float*)d_out;

  // workspace carve
  char* ws = (char*)d_ws;
  size_t off = 0;
  auto alloc = [&](size_t bytes) -> void* {
    void* p = ws + off;
    off = (off + bytes + 511) & ~(size_t)511;
    return p;
  };
  const size_t nf = (size_t)N * 128 * sizeof(float);
  float* P0 = (float*)alloc(nf);   // S0
  float* P1 = (float*)alloc(nf);   // S1 / g2
  float* P2 = (float*)alloc(nf);   // S2 / g3
  float* P3 = (float*)alloc(nf);   // S3
  float* P4 = (float*)alloc(nf);   // g1
  float* dinv = (float*)alloc((size_t)5 * N * sizeof(float));
  float* trel = (float*)alloc((size_t)N * sizeof(float));
  float* trot = (float*)alloc((size_t)N * sizeof(float));
  float* sco  = (float*)alloc((size_t)N * sizeof(float));
  int* rowptr = (int*)alloc((size_t)(N + 1) * sizeof(int));
  int* cnt    = (int*)alloc((size_t)N * sizeof(int));
  int* csr    = (int*)alloc((size_t)E * sizeof(int));
  int* csrSrc = (int*)alloc((size_t)E * sizeof(int));
  float4* csrW = (float4*)alloc((size_t)E * sizeof(float4));
  float* csrWO = (float*)alloc((size_t)E * sizeof(float));
  int* bsum   = (int*)alloc(1024);
  float* rbuf = (float*)alloc((size_t)Bg * 768 * sizeof(float));
  if (off > ws_size) return;

  const int nbN = (N + TPB - 1) / TPB;
  const int nbE = (E + TPB - 1) / TPB;
  const int nbGather = N / 8;       // 8000
  const int nbGemm = N / 64;        // 1000 (divisible by 8 for fconv swizzle)

  for (int br = 0; br < 2; ++br) {
    const int* erow = ei[br];
    const int* ecol = ei[br] + E;

    // CSR build (deterministic: sorted segments)
    hipMemsetAsync(cnt, 0, (size_t)N * sizeof(int), stream);
    count_k<<<nbE, TPB, 0, stream>>>(ecol, cnt, E);
    scan1_k<<<nbN, TPB, 0, stream>>>(cnt, rowptr, bsum, N);
    scan2_k<<<1, TPB, 0, stream>>>(bsum, nbN);
    scan3_k<<<nbN, TPB, 0, stream>>>(rowptr, bsum, N, E);
    hipMemsetAsync(cnt, 0, (size_t)N * sizeof(int), stream);
    fill_k<<<nbE, TPB, 0, stream>>>(ecol, rowptr, cnt, csr, E);
    sortadj_k<<<nbN, TPB, 0, stream>>>(rowptr, csr, N);
    deg_k<<<nbN, TPB, 0, stream>>>(rowptr, csr, eat[br], dinv, N);
    eresolve_k<<<nbE, TPB, 0, stream>>>(csr, erow, eat[br], dinv, N, E,
                                        csrSrc, csrW, csrWO);

    // conv1: fused 4-channel aggregate of x -> S0..S3, then fused 4-GEMM -> g1
    gather4_k<<<nbGather, 256, 0, stream>>>(
        (const float4*)x[br], rowptr, csrSrc, csrW, dinv, N,
        (float4*)P0, (float4*)P1, (float4*)P2, (float4*)P3);
    gemm4_k<<<nbGemm, 256, 0, stream>>>(P0, P1, P2, P3,
                                        W1[0], W1[1], W1[2], W1[3],
                                        b1[0], b1[1], b1[2], b1[3], P4, N);

    // conv2 fused: g2 = relu(agg(g1) @ W2 + b2) -> P1
    fconv_k<true><<<nbGemm, 256, 0, stream>>>(
        (const float4*)P4, rowptr, csrSrc, csrWO, dinv + (size_t)4 * N,
        W2, b2, P1, N);

    // conv3 fused: g3 = agg(g2) @ W3 + b3 -> P2
    fconv_k<false><<<nbGemm, 256, 0, stream>>>(
        (const float4*)P1, rowptr, csrSrc, csrWO, dinv + (size_t)4 * N,
        W3, b3, P2, N);

    // score + top-k pool (g1=P4, g2=P1, g3=P2)
    score_a<<<(N + 3) / 4, 256, 0, stream>>>(P4, P1, P2, Wsrel, Wsroot, trel, trot, N);
    score_b<<<nbN, TPB, 0, stream>>>(rowptr, csrSrc, trel, trot, bsrel, sco, N);
    topk_pool<<<Bg, 512, 0, stream>>>(sco, P4, P1, P2, rbuf, br, npg, kq);
  }

  mlp_k<<<Bg, 64, 0, stream>>>(rbuf, Wm1, bm1, Wm2, bm2, Wm3, bm3, out);
}

// Round 10
// 903.299 us; speedup vs baseline: 1.9599x; 1.0802x over previous
//
#include <hip/hip_runtime.h>
#include <math.h>

// ---------------------------------------------------------------------------
// PGCN twin-branch GCN. fp32. R10: R4 conv structure (gather1+gemm_epi
// unfused); CSR build merged across both branches (concatenated 2N/2E arrays,
// single scan); gemm4 split into two M-halves (profile visibility).
// All accumulation orders bitwise-identical to R4 (absmax 0).
// ---------------------------------------------------------------------------

#define TPB 256

__device__ __forceinline__ int swz_block(int bid, int nb) {
  int per = bid & 7;
  return per * (nb >> 3) + (bid >> 3);
}

__device__ __forceinline__ void f4fma(float4& a, const float4 b, float s) {
  a.x += b.x * s; a.y += b.y * s; a.z += b.z * s; a.w += b.w * s;
}
__device__ __forceinline__ float4 f4s(const float4 a, float s) {
  return make_float4(a.x * s, a.y * s, a.z * s, a.w * s);
}

// ---------------- merged CSR build (both branches, concatenated) ------------
// node space: [0,2N) = br*N + local; edge-slot space: [0,2E) = br*E + local.

__global__ __launch_bounds__(TPB) void count2_k(const int* __restrict__ ec0,
                                                const int* __restrict__ ec1,
                                                int* __restrict__ cnt, int E) {
  int e = blockIdx.x * TPB + threadIdx.x;
  if (e < 2 * E) {
    int br = e >= E;
    int el = e - br * E;
    int c = br ? ec1[el] : ec0[el];
    atomicAdd(&cnt[br * (gridDim.x * 0 + 0) + 0 + c + br * 64000], 1);
  }
}

// scan over 2N counts (512-thread blocks)
__global__ __launch_bounds__(512) void scan1_k(const int* __restrict__ cnt,
                                               int* __restrict__ rowptr,
                                               int* __restrict__ bsum, int tn) {
  __shared__ int s[512];
  int tid = threadIdx.x;
  int gid = blockIdx.x * 512 + tid;
  int v = (gid < tn) ? cnt[gid] : 0;
  s[tid] = v;
  __syncthreads();
  for (int o = 1; o < 512; o <<= 1) {
    int t = (tid >= o) ? s[tid - o] : 0;
    __syncthreads();
    s[tid] += t;
    __syncthreads();
  }
  if (gid < tn) rowptr[gid] = s[tid] - v;
  if (tid == 511) bsum[blockIdx.x] = s[511];
}

__global__ __launch_bounds__(TPB) void scan2_k(int* __restrict__ bsum, int nb) {
  __shared__ int s[TPB];
  int tid = threadIdx.x;
  int v = (tid < nb) ? bsum[tid] : 0;
  s[tid] = v;
  __syncthreads();
  for (int o = 1; o < TPB; o <<= 1) {
    int t = (tid >= o) ? s[tid - o] : 0;
    __syncthreads();
    s[tid] += t;
    __syncthreads();
  }
  if (tid < nb) bsum[tid] = s[tid] - v;
}

__global__ __launch_bounds__(512) void scan3_k(int* __restrict__ rowptr,
                                               const int* __restrict__ bsum,
                                               int tn, int tE) {
  int gid = blockIdx.x * 512 + threadIdx.x;
  if (gid < tn) rowptr[gid] += bsum[blockIdx.x];
  if (gid == 0) rowptr[tn] = tE;
}

__global__ __launch_bounds__(TPB) void fill2_k(const int* __restrict__ ec0,
                                               const int* __restrict__ ec1,
                                               const int* __restrict__ rowptr,
                                               int* __restrict__ fil,
                                               int* __restrict__ csr, int N,
                                               int E) {
  int e = blockIdx.x * TPB + threadIdx.x;
  if (e < 2 * E) {
    int br = e >= E;
    int el = e - br * E;
    int c = (br ? ec1[el] : ec0[el]) + br * N;
    int p = rowptr[c] + atomicAdd(&fil[c], 1);
    csr[p] = e;  // concatenated edge id
  }
}

__global__ __launch_bounds__(TPB) void sortadj_k(const int* __restrict__ rowptr,
                                                 int* __restrict__ csr, int tn) {
  int i = blockIdx.x * TPB + threadIdx.x;
  if (i >= tn) return;
  int s = rowptr[i], e = rowptr[i + 1];
  for (int a = s + 1; a < e; ++a) {
    int v = csr[a];
    int b = a - 1;
    while (b >= s && csr[b] > v) { csr[b + 1] = csr[b]; --b; }
    csr[b + 1] = v;
  }
}

// dinv layout: dinv[c*2N + gi], gi = br*N + local
__global__ __launch_bounds__(TPB) void deg2_k(const int* __restrict__ rowptr,
                                              const int* __restrict__ csr,
                                              const float* __restrict__ ea0,
                                              const float* __restrict__ ea1,
                                              float* __restrict__ dinv, int N,
                                              int E) {
  int i = blockIdx.x * TPB + threadIdx.x;
  int tn = 2 * N;
  if (i >= tn) return;
  int br = i >= N;
  const float* ea = br ? ea1 : ea0;
  int ebase = br * E;
  int s = rowptr[i], e = rowptr[i + 1];
  float d0 = 1.f, d1 = 1.f, d2 = 1.f, d3 = 1.f;
  for (int j = s; j < e; ++j) {
    int el = csr[j] - ebase;
    float4 w = *reinterpret_cast<const float4*>(&ea[(size_t)el * 4]);
    d0 += w.x; d1 += w.y; d2 += w.z; d3 += w.w;
  }
  float dO = (float)(e - s) + 1.f;
  dinv[0 * tn + i] = 1.f / sqrtf(d0);
  dinv[1 * tn + i] = 1.f / sqrtf(d1);
  dinv[2 * tn + i] = 1.f / sqrtf(d2);
  dinv[3 * tn + i] = 1.f / sqrtf(d3);
  dinv[4 * tn + i] = 1.f / sqrtf(dO);
}

__global__ __launch_bounds__(TPB) void eresolve2_k(
    const int* __restrict__ csr, const int* __restrict__ er0,
    const int* __restrict__ er1, const float* __restrict__ ea0,
    const float* __restrict__ ea1, const float* __restrict__ dinv, int N,
    int E, int* __restrict__ csrSrc, float4* __restrict__ csrW,
    float* __restrict__ csrWO) {
  int j = blockIdx.x * TPB + threadIdx.x;
  if (j >= 2 * E) return;
  int br = j >= E;  // slot space aligns with branch segments
  int tn = 2 * N;
  int el = csr[j] - br * E;
  int rl = br ? er1[el] : er0[el];
  int gi = br * N + rl;
  const float* ea = br ? ea1 : ea0;
  float4 a = *reinterpret_cast<const float4*>(&ea[(size_t)el * 4]);
  csrSrc[j] = rl;  // branch-local node id
  csrW[j] = make_float4(a.x * dinv[gi], a.y * dinv[tn + gi],
                        a.z * dinv[2 * tn + gi], a.w * dinv[3 * tn + gi]);
  csrWO[j] = dinv[4 * tn + gi];
}

// ------------- fused 4-channel gather on raw x -> S0..S3 ----------
// rowptr_b = rowptr + br*N (values are absolute into [0,2E));
// dinvp = dinv + br*N, channel stride tn.
__global__ __launch_bounds__(256) void gather4_k(
    const float4* __restrict__ X, const int* __restrict__ rowptr_b,
    const int* __restrict__ csrSrc, const float4* __restrict__ csrW,
    const float* __restrict__ dinvp, int tn, float4* __restrict__ S0,
    float4* __restrict__ S1, float4* __restrict__ S2, float4* __restrict__ S3) {
  int sb = swz_block(blockIdx.x, gridDim.x);
  int node = sb * 8 + (threadIdx.x >> 5);
  int l = threadIdx.x & 31;
  int s = rowptr_b[node], e = rowptr_b[node + 1];
  float d0 = dinvp[node], d1 = dinvp[tn + node], d2 = dinvp[2 * tn + node],
        d3 = dinvp[3 * tn + node];
  float4 xs = X[(size_t)node * 32 + l];
  float4 a0 = f4s(xs, d0), a1 = f4s(xs, d1), a2 = f4s(xs, d2), a3 = f4s(xs, d3);
  int j = s;
  for (; j + 3 < e; j += 4) {
    int r0 = csrSrc[j], r1 = csrSrc[j + 1], r2 = csrSrc[j + 2], r3 = csrSrc[j + 3];
    float4 w0 = csrW[j], w1 = csrW[j + 1], w2 = csrW[j + 2], w3 = csrW[j + 3];
    float4 x0 = X[(size_t)r0 * 32 + l];
    float4 x1 = X[(size_t)r1 * 32 + l];
    float4 x2 = X[(size_t)r2 * 32 + l];
    float4 x3 = X[(size_t)r3 * 32 + l];
    f4fma(a0, x0, w0.x); f4fma(a1, x0, w0.y); f4fma(a2, x0, w0.z); f4fma(a3, x0, w0.w);
    f4fma(a0, x1, w1.x); f4fma(a1, x1, w1.y); f4fma(a2, x1, w1.z); f4fma(a3, x1, w1.w);
    f4fma(a0, x2, w2.x); f4fma(a1, x2, w2.y); f4fma(a2, x2, w2.z); f4fma(a3, x2, w2.w);
    f4fma(a0, x3, w3.x); f4fma(a1, x3, w3.y); f4fma(a2, x3, w3.z); f4fma(a3, x3, w3.w);
  }
  for (; j < e; ++j) {
    int r = csrSrc[j];
    float4 w = csrW[j];
    float4 xr = X[(size_t)r * 32 + l];
    f4fma(a0, xr, w.x); f4fma(a1, xr, w.y); f4fma(a2, xr, w.z); f4fma(a3, xr, w.w);
  }
  size_t o = (size_t)node * 32 + l;
  S0[o] = f4s(a0, d0);
  S1[o] = f4s(a1, d1);
  S2[o] = f4s(a2, d2);
  S3[o] = f4s(a3, d3);
}

// ------------- single-channel gather (ones weights) ----------
__global__ __launch_bounds__(256) void gather1_k(
    const float4* __restrict__ X, const int* __restrict__ rowptr_b,
    const int* __restrict__ csrSrc, const float* __restrict__ csrWO,
    const float* __restrict__ dinvO, int N, float4* __restrict__ Out) {
  int sb = swz_block(blockIdx.x, gridDim.x);
  int node = sb * 8 + (threadIdx.x >> 5);
  int l = threadIdx.x & 31;
  int s = rowptr_b[node], e = rowptr_b[node + 1];
  float di = dinvO[node];
  float4 acc = f4s(X[(size_t)node * 32 + l], di);
  int j = s;
  for (; j + 3 < e; j += 4) {
    int r0 = csrSrc[j], r1 = csrSrc[j + 1], r2 = csrSrc[j + 2], r3 = csrSrc[j + 3];
    float w0 = csrWO[j], w1 = csrWO[j + 1], w2 = csrWO[j + 2], w3 = csrWO[j + 3];
    float4 x0 = X[(size_t)r0 * 32 + l];
    float4 x1 = X[(size_t)r1 * 32 + l];
    float4 x2 = X[(size_t)r2 * 32 + l];
    float4 x3 = X[(size_t)r3 * 32 + l];
    f4fma(acc, x0, w0); f4fma(acc, x1, w1); f4fma(acc, x2, w2); f4fma(acc, x3, w3);
  }
  for (; j < e; ++j) {
    f4fma(acc, X[(size_t)csrSrc[j] * 32 + l], csrWO[j]);
  }
  Out[(size_t)node * 32 + l] = f4s(acc, di);
}

// ---------------- GEMM with bias(+relu) epilogue (exact R4) ----------------
template <bool RELU>
__global__ __launch_bounds__(256) void gemm_epi(const float* __restrict__ A,
                                                const float* __restrict__ W,
                                                const float* __restrict__ bias,
                                                float* __restrict__ C, int M) {
  __shared__ float As[64][64];
  __shared__ float Ws[64][128];
  int tid = threadIdx.x;
  int tx = tid & 31;
  int ty = tid >> 5;
  int rowBase = blockIdx.x * 64;
  float acc[8][4] = {};
  for (int kc = 0; kc < 128; kc += 64) {
#pragma unroll
    for (int i = 0; i < 4; ++i) {
      int idx = tid + i * 256;
      int r = idx >> 4;
      int c4 = idx & 15;
      *reinterpret_cast<float4*>(&As[r][c4 * 4]) =
          *reinterpret_cast<const float4*>(&A[(size_t)(rowBase + r) * 128 + kc + c4 * 4]);
    }
#pragma unroll
    for (int i = 0; i < 8; ++i) {
      int idx = tid + i * 256;
      int r = idx >> 5;
      int c4 = idx & 31;
      *reinterpret_cast<float4*>(&Ws[r][c4 * 4]) =
          *reinterpret_cast<const float4*>(&W[(size_t)(kc + r) * 128 + c4 * 4]);
    }
    __syncthreads();
#pragma unroll 4
    for (int k = 0; k < 64; ++k) {
      float b0[4];
      *reinterpret_cast<float4*>(b0) = *reinterpret_cast<const float4*>(&Ws[k][tx * 4]);
#pragma unroll
      for (int j = 0; j < 8; ++j) {
        float a = As[ty * 8 + j][k];
        acc[j][0] += a * b0[0];
        acc[j][1] += a * b0[1];
        acc[j][2] += a * b0[2];
        acc[j][3] += a * b0[3];
      }
    }
    __syncthreads();
  }
  float4 bq = *reinterpret_cast<const float4*>(&bias[tx * 4]);
#pragma unroll
  for (int j = 0; j < 8; ++j) {
    float v0 = acc[j][0] + bq.x, v1 = acc[j][1] + bq.y, v2 = acc[j][2] + bq.z,
          v3 = acc[j][3] + bq.w;
    if (RELU) {
      v0 = fmaxf(v0, 0.f); v1 = fmaxf(v1, 0.f); v2 = fmaxf(v2, 0.f); v3 = fmaxf(v3, 0.f);
    }
    size_t r = (size_t)(rowBase + ty * 8 + j) * 128 + tx * 4;
    *reinterpret_cast<float4*>(&C[r]) = make_float4(v0, v1, v2, v3);
  }
}

// ---------------- gemm4 (exact R4 math, M-half per launch) ----------------
__global__ __launch_bounds__(256) void gemm4_k(
    const float* __restrict__ S0, const float* __restrict__ S1,
    const float* __restrict__ S2, const float* __restrict__ S3,
    const float* __restrict__ W0, const float* __restrict__ W1,
    const float* __restrict__ W2, const float* __restrict__ W3,
    const float* __restrict__ B0, const float* __restrict__ B1,
    const float* __restrict__ B2, const float* __restrict__ B3,
    float* __restrict__ g1, int tileBase) {
  __shared__ float As[64][64];
  __shared__ float Ws[64][128];
  const float* Sarr[4] = {S0, S1, S2, S3};
  const float* Warr[4] = {W0, W1, W2, W3};
  const float* Barr[4] = {B0, B1, B2, B3};
  int tid = threadIdx.x;
  int tx = tid & 31;
  int ty = tid >> 5;
  int rowBase = (tileBase + blockIdx.x) * 64;
  float facc[8][4] = {};
#pragma unroll
  for (int q = 0; q < 4; ++q) {
    const float* A = Sarr[q];
    const float* W = Warr[q];
    float acc[8][4] = {};
    for (int kc = 0; kc < 128; kc += 64) {
#pragma unroll
      for (int i = 0; i < 4; ++i) {
        int idx = tid + i * 256;
        int r = idx >> 4;
        int c4 = idx & 15;
        *reinterpret_cast<float4*>(&As[r][c4 * 4]) =
            *reinterpret_cast<const float4*>(&A[(size_t)(rowBase + r) * 128 + kc + c4 * 4]);
      }
#pragma unroll
      for (int i = 0; i < 8; ++i) {
        int idx = tid + i * 256;
        int r = idx >> 5;
        int c4 = idx & 31;
        *reinterpret_cast<float4*>(&Ws[r][c4 * 4]) =
            *reinterpret_cast<const float4*>(&W[(size_t)(kc + r) * 128 + c4 * 4]);
      }
      __syncthreads();
#pragma unroll 4
      for (int k = 0; k < 64; ++k) {
        float b0[4];
        *reinterpret_cast<float4*>(b0) = *reinterpret_cast<const float4*>(&Ws[k][tx * 4]);
#pragma unroll
        for (int j = 0; j < 8; ++j) {
          float a = As[ty * 8 + j][k];
          acc[j][0] += a * b0[0];
          acc[j][1] += a * b0[1];
          acc[j][2] += a * b0[2];
          acc[j][3] += a * b0[3];
        }
      }
      __syncthreads();
    }
    float4 bq = *reinterpret_cast<const float4*>(&Barr[q][tx * 4]);
#pragma unroll
    for (int j = 0; j < 8; ++j) {
      facc[j][0] += fmaxf(acc[j][0] + bq.x, 0.f) * 0.25f;
      facc[j][1] += fmaxf(acc[j][1] + bq.y, 0.f) * 0.25f;
      facc[j][2] += fmaxf(acc[j][2] + bq.z, 0.f) * 0.25f;
      facc[j][3] += fmaxf(acc[j][3] + bq.w, 0.f) * 0.25f;
    }
  }
#pragma unroll
  for (int j = 0; j < 8; ++j) {
    size_t r = (size_t)(rowBase + ty * 8 + j) * 128 + tx * 4;
    *reinterpret_cast<float4*>(&g1[r]) =
        make_float4(facc[j][0], facc[j][1], facc[j][2], facc[j][3]);
  }
}

// ------------- score -------------
__global__ __launch_bounds__(256) void score_a(
    const float* __restrict__ g1, const float* __restrict__ g2,
    const float* __restrict__ g3, const float* __restrict__ Wrel,
    const float* __restrict__ Wroot, float* __restrict__ trel,
    float* __restrict__ troot, int N) {
  int wave = threadIdx.x >> 6;
  int lane = threadIdx.x & 63;
  int node = blockIdx.x * 4 + wave;
  if (node >= N) return;
  float sr = 0.f, so = 0.f;
#pragma unroll
  for (int t = 0; t < 2; ++t) {
    int f = lane + t * 64;
    float v1 = g1[(size_t)node * 128 + f];
    float v2 = g2[(size_t)node * 128 + f];
    float v3 = g3[(size_t)node * 128 + f];
    sr += v1 * Wrel[f] + v2 * Wrel[128 + f] + v3 * Wrel[256 + f];
    so += v1 * Wroot[f] + v2 * Wroot[128 + f] + v3 * Wroot[256 + f];
  }
  for (int off = 32; off; off >>= 1) {
    sr += __shfl_down(sr, off);
    so += __shfl_down(so, off);
  }
  if (lane == 0) { trel[node] = sr; troot[node] = so; }
}

__global__ __launch_bounds__(TPB) void score_b(
    const int* __restrict__ rowptr_b, const int* __restrict__ csrSrc,
    const float* __restrict__ trel, const float* __restrict__ troot,
    const float* __restrict__ bs, float* __restrict__ score, int N) {
  int i = blockIdx.x * TPB + threadIdx.x;
  if (i >= N) return;
  float sc = bs[0] + troot[i];
  int s = rowptr_b[i], e = rowptr_b[i + 1];
  for (int j = s; j < e; ++j) sc += trel[csrSrc[j]];
  score[i] = sc;
}

// ------------- per-graph top-k (bitonic) + tanh-weighted mean pool -------------
__global__ __launch_bounds__(512) void topk_pool(
    const float* __restrict__ score, const float* __restrict__ g1,
    const float* __restrict__ g2, const float* __restrict__ g3,
    float* __restrict__ r, int half, int npg, int k) {
  __shared__ float key[1024];
  __shared__ int idx[1024];
  __shared__ float wts[512];
  int b = blockIdx.x;
  int tid = threadIdx.x;
  int base = b * npg;
  for (int i = tid; i < 1024; i += 512) {
    key[i] = (i < npg) ? score[base + i] : -3.0e38f;
    idx[i] = i;
  }
  __syncthreads();
  for (int kk = 2; kk <= 1024; kk <<= 1) {
    for (int j = kk >> 1; j > 0; j >>= 1) {
      for (int i = tid; i < 1024; i += 512) {
        int ixj = i ^ j;
        if (ixj > i) {
          bool desc = ((i & kk) == 0);
          float ki = key[i], kj = key[ixj];
          bool sw = desc ? (ki < kj) : (ki > kj);
          if (sw) {
            key[i] = kj; key[ixj] = ki;
            int t = idx[i]; idx[i] = idx[ixj]; idx[ixj] = t;
          }
        }
      }
      __syncthreads();
    }
  }
  if (tid < k) wts[tid] = tanhf(key[tid]);
  __syncthreads();
  if (tid < 384) {
    const float* gp = (tid < 128) ? g1 : ((tid < 256) ? g2 : g3);
    int fo = tid & 127;
    float acc = 0.f;
    for (int j = 0; j < k; ++j) {
      int n = base + idx[j];
      acc += wts[j] * gp[(size_t)n * 128 + fo];
    }
    r[(size_t)b * 768 + half * 384 + tid] = acc / (float)k;
  }
}

// ------------- MLP 768 -> 32 -> 8 -> 2 -------------
__global__ __launch_bounds__(64) void mlp_k(
    const float* __restrict__ r, const float* __restrict__ Wm1,
    const float* __restrict__ bm1, const float* __restrict__ Wm2,
    const float* __restrict__ bm2, const float* __restrict__ Wm3,
    const float* __restrict__ bm3, float* __restrict__ out) {
  __shared__ float rr[768];
  __shared__ float h1[32];
  __shared__ float h2[8];
  int b = blockIdx.x;
  int tid = threadIdx.x;
  for (int i = tid; i < 768; i += 64) rr[i] = r[(size_t)b * 768 + i];
  __syncthreads();
  if (tid < 32) {
    float s = bm1[tid];
    for (int i = 0; i < 768; ++i) s += rr[i] * Wm1[i * 32 + tid];
    h1[tid] = fmaxf(s, 0.f);
  }
  __syncthreads();
  if (tid < 8) {
    float s = bm2[tid];
    for (int i = 0; i < 32; ++i) s += h1[i] * Wm2[i * 8 + tid];
    h2[tid] = fmaxf(s, 0.f);
  }
  __syncthreads();
  if (tid < 2) {
    float s = bm3[tid];
    for (int i = 0; i < 8; ++i) s += h2[i] * Wm3[i * 2 + tid];
    out[b * 2 + tid] = s;
  }
}

// ---------------------------------------------------------------------------
extern "C" void kernel_launch(void* const* d_in, const int* in_sizes, int n_in,
                              void* d_out, int out_size, void* d_ws, size_t ws_size,
                              hipStream_t stream) {
  const float* x[2]  = {(const float*)d_in[0], (const float*)d_in[3]};
  const float* eat[2] = {(const float*)d_in[1], (const float*)d_in[4]};
  const int*   ei[2] = {(const int*)d_in[2], (const int*)d_in[5]};
  const int N = in_sizes[0] / 128;   // 64000
  const int E = in_sizes[2] / 2;     // 512000
  const int tn = 2 * N;
  const int tE = 2 * E;
  const int Bg = 64;
  const int npg = N / Bg;            // 1000
  const int kq = npg / 2;            // 500

  const float* W1[4] = {(const float*)d_in[9], (const float*)d_in[11],
                        (const float*)d_in[13], (const float*)d_in[15]};
  const float* b1[4] = {(const float*)d_in[10], (const float*)d_in[12],
                        (const float*)d_in[14], (const float*)d_in[16]};
  const float* W2 = (const float*)d_in[17];
  const float* b2 = (const float*)d_in[18];
  const float* W3 = (const float*)d_in[19];
  const float* b3 = (const float*)d_in[20];
  const float* Wsrel  = (const float*)d_in[21];
  const float* bsrel  = (const float*)d_in[22];
  const float* Wsroot = (const float*)d_in[23];
  const float* Wm1 = (const float*)d_in[24];
  const float* bm1 = (const float*)d_in[25];
  const float* Wm2 = (const float*)d_in[26];
  const float* bm2 = (const float*)d_in[27];
  const float* Wm3 = (const float*)d_in[28];
  const float* bm3 = (const float*)d_in[29];
  float* out = (float*)d_out;

  // workspace carve
  char* ws = (char*)d_ws;
  size_t off = 0;
  auto alloc = [&](size_t bytes) -> void* {
    void* p = ws + off;
    off = (off + bytes + 511) & ~(size_t)511;
    return p;
  };
  const size_t nf = (size_t)N * 128 * sizeof(float);
  float* P0 = (float*)alloc(nf);   // S0 / agg
  float* P1 = (float*)alloc(nf);   // S1 / g2
  float* P2 = (float*)alloc(nf);   // S2 / g3
  float* P3 = (float*)alloc(nf);   // S3
  float* P4 = (float*)alloc(nf);   // g1
  float* dinv = (float*)alloc((size_t)5 * tn * sizeof(float));
  float* trel = (float*)alloc((size_t)N * sizeof(float));
  float* trot = (float*)alloc((size_t)N * sizeof(float));
  float* sco  = (float*)alloc((size_t)N * sizeof(float));
  int* rowptr = (int*)alloc((size_t)(tn + 1) * sizeof(int));
  int* cnt    = (int*)alloc((size_t)tn * sizeof(int));
  int* csr    = (int*)alloc((size_t)tE * sizeof(int));
  int* csrSrc = (int*)alloc((size_t)tE * sizeof(int));
  float4* csrW = (float4*)alloc((size_t)tE * sizeof(float4));
  float* csrWO = (float*)alloc((size_t)tE * sizeof(float));
  int* bsum   = (int*)alloc(1024);
  float* rbuf = (float*)alloc((size_t)Bg * 768 * sizeof(float));
  if (off > ws_size) return;

  const int nbN2 = (tn + TPB - 1) / TPB;    // 500
  const int nbE2 = (tE + TPB - 1) / TPB;    // 4000
  const int nbS  = (tn + 511) / 512;        // 250 (scan blocks)
  const int nbN  = (N + TPB - 1) / TPB;     // 250
  const int nbGather = N / 8;               // 8000
  const int nbGemm = N / 64;                // 1000
  const int nbGemmHalf = nbGemm / 2;        // 500

  // ---- merged CSR build for both branches ----
  hipMemsetAsync(cnt, 0, (size_t)tn * sizeof(int), stream);
  count2_k<<<nbE2, TPB, 0, stream>>>(ei[0] + E, ei[1] + E, cnt, E);
  scan1_k<<<nbS, 512, 0, stream>>>(cnt, rowptr, bsum, tn);
  scan2_k<<<1, TPB, 0, stream>>>(bsum, nbS);
  scan3_k<<<nbS, 512, 0, stream>>>(rowptr, bsum, tn, tE);
  hipMemsetAsync(cnt, 0, (size_t)tn * sizeof(int), stream);
  fill2_k<<<nbE2, TPB, 0, stream>>>(ei[0] + E, ei[1] + E, rowptr, cnt, csr, N, E);
  sortadj_k<<<nbN2, TPB, 0, stream>>>(rowptr, csr, tn);
  deg2_k<<<nbN2, TPB, 0, stream>>>(rowptr, csr, eat[0], eat[1], dinv, N, E);
  eresolve2_k<<<nbE2, TPB, 0, stream>>>(csr, ei[0], ei[1], eat[0], eat[1],
                                        dinv, N, E, csrSrc, csrW, csrWO);

  for (int br = 0; br < 2; ++br) {
    const int* rowptr_b = rowptr + (size_t)br * N;
    const float* dinvp = dinv + (size_t)br * N;          // channel stride tn
    const float* dinvO = dinv + (size_t)4 * tn + (size_t)br * N;

    // conv1: fused 4-channel aggregate -> S0..S3, then fused 4-GEMM -> g1 (P4)
    gather4_k<<<nbGather, 256, 0, stream>>>(
        (const float4*)x[br], rowptr_b, csrSrc, csrW, dinvp, tn,
        (float4*)P0, (float4*)P1, (float4*)P2, (float4*)P3);
    gemm4_k<<<nbGemmHalf, 256, 0, stream>>>(P0, P1, P2, P3,
                                            W1[0], W1[1], W1[2], W1[3],
                                            b1[0], b1[1], b1[2], b1[3], P4, 0);
    gemm4_k<<<nbGemmHalf, 256, 0, stream>>>(P0, P1, P2, P3,
                                            W1[0], W1[1], W1[2], W1[3],
                                            b1[0], b1[1], b1[2], b1[3], P4,
                                            nbGemmHalf);

    // conv2: aggregate g1 -> P0, g2 = relu(P0 @ W2 + b2) -> P1
    gather1_k<<<nbGather, 256, 0, stream>>>(
        (const float4*)P4, rowptr_b, csrSrc, csrWO, dinvO, N, (float4*)P0);
    gemm_epi<true><<<nbGemm, 256, 0, stream>>>(P0, W2, b2, P1, N);

    // conv3: aggregate g2 -> P0, g3 = P0 @ W3 + b3 -> P2
    gather1_k<<<nbGather, 256, 0, stream>>>(
        (const float4*)P1, rowptr_b, csrSrc, csrWO, dinvO, N, (float4*)P0);
    gemm_epi<false><<<nbGemm, 256, 0, stream>>>(P0, W3, b3, P2, N);

    // score + top-k pool (g1=P4, g2=P1, g3=P2)
    score_a<<<(N + 3) / 4, 256, 0, stream>>>(P4, P1, P2, Wsrel, Wsroot, trel, trot, N);
    score_b<<<nbN, TPB, 0, stream>>>(rowptr_b, csrSrc, trel, trot, bsrel, sco, N);
    topk_pool<<<Bg, 512, 0, stream>>>(sco, P4, P1, P2, rbuf, br, npg, kq);
  }

  mlp_k<<<Bg, 64, 0, stream>>>(rbuf, Wm1, bm1, Wm2, bm2, Wm3, bm3, out);
}